// Round 3
// baseline (389.187 us; speedup 1.0000x reference)
//
#include <hip/hip_runtime.h>
#include <math.h>

#define N 4096
#define DIN 512
#define D 32
#define JC 8

// ---------------- encoder: x[4096,512] -> latent[4096,32] + normed rows, fused ----------------
// R3: 4 rows/block (grid 1024 = 4 blocks/CU = 16 waves/CU; R2's 512-block config sat at
// VALUBusy 11% / Occ 21% -- pure L2-latency stall on the 512-deep k-loop). More resident
// waves is the latency-hiding lever; extra w1 L2 re-reads (256 MB) cost ~7 us of L2 BW.
__global__ __launch_bounds__(256) void enc_kernel(
    const float* __restrict__ x,
    const float* __restrict__ w1, const float* __restrict__ b1,
    const float* __restrict__ w2, const float* __restrict__ b2,
    const float* __restrict__ w3, const float* __restrict__ b3,
    float* __restrict__ latent, float* __restrict__ normed) {
  __shared__ float xs[4][512];
  __shared__ float h1s[4][128];
  __shared__ float h2s[4][64];
  const int t = threadIdx.x;
  const int r0 = blockIdx.x * 4;

  const float4* xg = (const float4*)(x + (size_t)r0 * DIN);
  float4* xl = (float4*)&xs[0][0];
  xl[t] = xg[t];
  xl[t + 256] = xg[t + 256];
  __syncthreads();

  // layer 1: 512 -> 128, relu. thread: 1 row (t>>6) x 2 cols ((t&63)*2)
  {
    const int jc2 = (t & 63) * 2;
    const int r = t >> 6;
    float a0 = b1[jc2], a1 = b1[jc2 + 1];
#pragma unroll 2
    for (int kk = 0; kk < 512; kk += 4) {
      const float4 xa = *(const float4*)&xs[r][kk];
      const float2 w0 = *(const float2*)&w1[(size_t)(kk + 0) * 128 + jc2];
      const float2 wA = *(const float2*)&w1[(size_t)(kk + 1) * 128 + jc2];
      const float2 wB = *(const float2*)&w1[(size_t)(kk + 2) * 128 + jc2];
      const float2 wC = *(const float2*)&w1[(size_t)(kk + 3) * 128 + jc2];
      a0 = fmaf(xa.x, w0.x, a0); a1 = fmaf(xa.x, w0.y, a1);
      a0 = fmaf(xa.y, wA.x, a0); a1 = fmaf(xa.y, wA.y, a1);
      a0 = fmaf(xa.z, wB.x, a0); a1 = fmaf(xa.z, wB.y, a1);
      a0 = fmaf(xa.w, wC.x, a0); a1 = fmaf(xa.w, wC.y, a1);
    }
    h1s[r][jc2] = fmaxf(a0, 0.f);
    h1s[r][jc2 + 1] = fmaxf(a1, 0.f);
  }
  __syncthreads();

  // layer 2: 128 -> 64, relu. thread: 1 row (t>>6) x 1 col (t&63)
  {
    const int j = t & 63, r = t >> 6;
    float a = b2[j];
#pragma unroll 4
    for (int kk = 0; kk < 128; ++kk) a = fmaf(h1s[r][kk], w2[kk * 64 + j], a);
    h2s[r][j] = fmaxf(a, 0.f);
  }
  __syncthreads();

  // layer 3: 64 -> 32 + fused row-normalize (shfl reduce over the 32 j-lanes)
  if (t < 128) {
    const int j = t & 31, r = t >> 5;
    float acc = b3[j];
#pragma unroll 4
    for (int kk = 0; kk < 64; ++kk) acc = fmaf(h2s[r][kk], w3[kk * 32 + j], acc);
    float s2 = acc * acc;
    s2 += __shfl_xor(s2, 1);
    s2 += __shfl_xor(s2, 2);
    s2 += __shfl_xor(s2, 4);
    s2 += __shfl_xor(s2, 8);
    s2 += __shfl_xor(s2, 16);
    const float inv = 1.0f / (sqrtf(s2) + 1e-12f);
    const size_t off = (size_t)(r0 + r) * D + j;
    latent[off] = acc;
    normed[off] = acc * inv;
  }
}

// ---------------- graph pool partials: block (bi, bj) covers 64 i-rows x 512 j ----------------
__global__ __launch_bounds__(256) void pool_kernel(const float* __restrict__ normed,
                                                   const float* __restrict__ latent,
                                                   float* __restrict__ pacc,
                                                   float* __restrict__ pdeg) {
  __shared__ float smem[8192 + 256];
  float* nt = smem;
  float* lt = smem + 4096;
  float* degr = smem + 8192;
  const int t = threadIdx.x;
  const int il = t & 63, g = t >> 6;
  const int i0 = blockIdx.x * 64;
  const int j0 = blockIdx.y * 512;

  float ni[32];
  const float* nrow = normed + (size_t)(i0 + il) * D;
#pragma unroll
  for (int c = 0; c < 32; ++c) ni[c] = nrow[c];

  float acc[32];
#pragma unroll
  for (int c = 0; c < 32; ++c) acc[c] = 0.f;
  float deg = 0.f;

  for (int jt = j0; jt < j0 + 512; jt += 128) {
    __syncthreads();
    const float4* ng = (const float4*)(normed + (size_t)jt * D);
    const float4* lg = (const float4*)(latent + (size_t)jt * D);
    float4* ntl = (float4*)nt;
    float4* ltl = (float4*)lt;
#pragma unroll
    for (int i = 0; i < 4; ++i) {
      ntl[t + i * 256] = ng[t + i * 256];
      ltl[t + i * 256] = lg[t + i * 256];
    }
    __syncthreads();
    for (int jj = g; jj < 128; jj += 4) {
      const float* nr = nt + jj * 32;
      float s = 0.f;
#pragma unroll
      for (int c = 0; c < 32; ++c) s = fmaf(ni[c], nr[c], s);
      if (s >= 0.9f) {
        deg += 1.f;
        const float* lrow = lt + jj * 32;
#pragma unroll
        for (int c = 0; c < 32; ++c) acc[c] += lrow[c];
      }
    }
  }
  __syncthreads();
  float* accr = smem;
#pragma unroll
  for (int c = 0; c < 32; ++c) accr[(g * 64 + il) * 32 + c] = acc[c];
  degr[t] = deg;
  __syncthreads();
  for (int e = t; e < 64 * 32; e += 256) {
    const float s = accr[e] + accr[2048 + e] + accr[4096 + e] + accr[6144 + e];
    pacc[((size_t)blockIdx.y * N + i0 + (e >> 5)) * 32 + (e & 31)] = s;
  }
  if (t < 64) {
    pdeg[(size_t)blockIdx.y * N + i0 + t] = degr[t] + degr[64 + t] + degr[128 + t] + degr[192 + t];
  }
}

// ---------------- combine pool partials -> h = latent + (mask@latent)/deg ----------------
__global__ __launch_bounds__(256) void pool_combine(const float* __restrict__ latent,
                                                    const float* __restrict__ pacc,
                                                    const float* __restrict__ pdeg,
                                                    float* __restrict__ h) {
  const int e = blockIdx.x * 256 + threadIdx.x;
  const int i = e >> 5;
  float s = 0.f, dg = 0.f;
#pragma unroll
  for (int gch = 0; gch < JC; ++gch) {
    s += pacc[(size_t)gch * N * 32 + e];
    dg += pdeg[(size_t)gch * N + i];
  }
  h[e] = latent[e] + s / dg;
}

// ---------------- fused QKV projection (q pre-scaled by log2e/sqrt(8)) + k-norm max ----------------
__global__ __launch_bounds__(256) void qkv_kernel(
    const float* __restrict__ h,
    const float* __restrict__ wq, const float* __restrict__ bq,
    const float* __restrict__ wk, const float* __restrict__ bk,
    const float* __restrict__ wv, const float* __restrict__ bv,
    float* __restrict__ q, float* __restrict__ k, float* __restrict__ v,
    int* __restrict__ kmax2i) {
  __shared__ float hs[32][32];
  __shared__ float wsm[3][32][32];
  __shared__ int kred[4];
  const int t = threadIdx.x;
  const int r0 = blockIdx.x * 32;
  if (t < 4) kred[t] = 0;
  ((float4*)&hs[0][0])[t] = ((const float4*)(h + (size_t)r0 * 32))[t];
  ((float4*)&wsm[0][0][0])[t] = ((const float4*)wq)[t];
  ((float4*)&wsm[1][0][0])[t] = ((const float4*)wk)[t];
  ((float4*)&wsm[2][0][0])[t] = ((const float4*)wv)[t];
  __syncthreads();
  const int j = t & 31, og = t >> 5;
  const int head = j >> 3;
  float aq[4], ak[4], av[4];
#pragma unroll
  for (int u = 0; u < 4; ++u) { aq[u] = bq[j]; ak[u] = bk[j]; av[u] = bv[j]; }
  for (int kk = 0; kk < 32; ++kk) {
    const float wqv = wsm[0][kk][j], wkv = wsm[1][kk][j], wvv = wsm[2][kk][j];
#pragma unroll
    for (int u = 0; u < 4; ++u) {
      const float hh = hs[og * 4 + u][kk];
      aq[u] = fmaf(hh, wqv, aq[u]);
      ak[u] = fmaf(hh, wkv, ak[u]);
      av[u] = fmaf(hh, wvv, av[u]);
    }
  }
  const float scale = 1.4426950408889634f * 0.35355339059327373f;  // log2(e)/sqrt(8)
#pragma unroll
  for (int u = 0; u < 4; ++u) {
    const size_t off = (size_t)(r0 + og * 4 + u) * 32 + j;
    q[off] = aq[u] * scale;
    k[off] = ak[u];
    v[off] = av[u];
  }
  // per-(row,head) ||k8||^2 via shfl over the 8 lanes of this head; block-max; global atomicMax
#pragma unroll
  for (int u = 0; u < 4; ++u) {
    float s2 = ak[u] * ak[u];
    s2 += __shfl_xor(s2, 1);
    s2 += __shfl_xor(s2, 2);
    s2 += __shfl_xor(s2, 4);
    if ((j & 7) == 0) atomicMax(&kred[head], __float_as_int(s2));
  }
  __syncthreads();
  if (t < 4) atomicMax(&kmax2i[t], kred[t]);
}

// ---------------- attention partials: block (rowBlk, jChunk); 32 rows x 512 j ----------------
// R3: NO LDS. R2's counters proved LDS-throughput-bound: 2.1M wave ds_read_b128 (~41 us)
// + 8.4M conflict-cycles (~14 us) = 55 us measured. The 4-way b128 conflict is structural
// (32 lanes x 32 distinct rows over 8 float4 slots). Instead each thread streams its own
// head's 8 k-floats + 8 v-floats per j-row straight from global -- k/v are 512 KB, fully
// L2-resident; rg-duplicate lanes coalesce to the same lines so unique traffic ~535 MB.
// u=4 rows/thread amortizes each 64 B k/v read over 4 q-rows. No barriers at all.
// j-order per thread identical to R2 (jg-strided, butterfly over lane bits 0..2).
__global__ __launch_bounds__(256, 4) void attn_kernel(const float* __restrict__ q,
                                                      const float* __restrict__ k,
                                                      const float* __restrict__ v,
                                                      const int* __restrict__ kmax2i,
                                                      float* __restrict__ apacc,
                                                      float* __restrict__ apl) {
  const int t = threadIdx.x;
  const int jg = t & 7, head = (t >> 3) & 3, rg = t >> 5;
  const int r0 = blockIdx.x * 32;
  const int j0 = blockIdx.y * (N / JC);

  const float km2 = __int_as_float(kmax2i[head]);

  float4 qa[4], qb[4], accA[4], accB[4];
  float mneg[4], l[4];
#pragma unroll
  for (int u = 0; u < 4; ++u) {
    const float* qr = q + (size_t)(r0 + rg * 4 + u) * 32 + head * 8;
    qa[u] = ((const float4*)qr)[0];
    qb[u] = ((const float4*)qr)[1];
    const float qn2 = qa[u].x * qa[u].x + qa[u].y * qa[u].y + qa[u].z * qa[u].z + qa[u].w * qa[u].w +
                      qb[u].x * qb[u].x + qb[u].y * qb[u].y + qb[u].z * qb[u].z + qb[u].w * qb[u].w;
    mneg[u] = -sqrtf(qn2 * km2);
    l[u] = 0.f;
    accA[u] = make_float4(0.f, 0.f, 0.f, 0.f);
    accB[u] = make_float4(0.f, 0.f, 0.f, 0.f);
  }

  // per-lane stream base: row (j0+jg), this head's 8-float slice; advance 8 rows/iter
  const float4* kg = (const float4*)(k + (size_t)(j0 + jg) * 32 + head * 8);
  const float4* vg = (const float4*)(v + (size_t)(j0 + jg) * 32 + head * 8);
#pragma unroll 2
  for (int it = 0; it < (N / JC) / 8; ++it) {
    const size_t off = (size_t)it * 64;  // 8 rows * 8 float4/row
    const float4 ka = kg[off];
    const float4 kb = kg[off + 1];
    const float4 va = vg[off];
    const float4 vb = vg[off + 1];
#pragma unroll
    for (int u = 0; u < 4; ++u) {
      float s = fmaf(qa[u].x, ka.x, mneg[u]);
      s = fmaf(qa[u].y, ka.y, s);
      s = fmaf(qa[u].z, ka.z, s);
      s = fmaf(qa[u].w, ka.w, s);
      s = fmaf(qb[u].x, kb.x, s);
      s = fmaf(qb[u].y, kb.y, s);
      s = fmaf(qb[u].z, kb.z, s);
      s = fmaf(qb[u].w, kb.w, s);
      const float p = __builtin_amdgcn_exp2f(s);
      l[u] += p;
      accA[u].x = fmaf(p, va.x, accA[u].x);
      accA[u].y = fmaf(p, va.y, accA[u].y);
      accA[u].z = fmaf(p, va.z, accA[u].z);
      accA[u].w = fmaf(p, va.w, accA[u].w);
      accB[u].x = fmaf(p, vb.x, accB[u].x);
      accB[u].y = fmaf(p, vb.y, accB[u].y);
      accB[u].z = fmaf(p, vb.z, accB[u].z);
      accB[u].w = fmaf(p, vb.w, accB[u].w);
    }
  }
  // butterfly-reduce the 8 jg partials (jg = lane bits 0..2); all lanes end with the sum
#pragma unroll
  for (int u = 0; u < 4; ++u) {
#pragma unroll
    for (int m = 1; m <= 4; m <<= 1) {
      accA[u].x += __shfl_xor(accA[u].x, m);
      accA[u].y += __shfl_xor(accA[u].y, m);
      accA[u].z += __shfl_xor(accA[u].z, m);
      accA[u].w += __shfl_xor(accA[u].w, m);
      accB[u].x += __shfl_xor(accB[u].x, m);
      accB[u].y += __shfl_xor(accB[u].y, m);
      accB[u].z += __shfl_xor(accB[u].z, m);
      accB[u].w += __shfl_xor(accB[u].w, m);
      l[u] += __shfl_xor(l[u], m);
    }
  }
  if (jg == 0) {
#pragma unroll
    for (int u = 0; u < 4; ++u) {
      const int row = r0 + rg * 4 + u;
      float* ap = apacc + (size_t)blockIdx.y * N * 32 + (size_t)row * 32 + head * 8;
      ((float4*)ap)[0] = accA[u];
      ((float4*)ap)[1] = accB[u];
      apl[(size_t)blockIdx.y * N * 4 + (size_t)row * 4 + head] = l[u];
    }
  }
}

// ---------------- combine attention partials ----------------
__global__ __launch_bounds__(256) void acombine(const float* __restrict__ apacc,
                                                const float* __restrict__ apl,
                                                float* __restrict__ attno) {
  const int e = blockIdx.x * 256 + threadIdx.x;  // < N*32
  const int row = e >> 5;
  const int hh = (e >> 3) & 3;
  float L = 0.f, S = 0.f;
#pragma unroll
  for (int jc = 0; jc < JC; ++jc) {
    L += apl[(size_t)jc * N * 4 + row * 4 + hh];
    S += apacc[(size_t)jc * N * 32 + e];
  }
  attno[e] = S / L;
}

// ---------------- O-projection + residual + LayerNorm1 ----------------
__global__ __launch_bounds__(256) void oln1_kernel(const float* __restrict__ attno,
                                                   const float* __restrict__ wo,
                                                   const float* __restrict__ bo,
                                                   const float* __restrict__ g,
                                                   const float* __restrict__ b,
                                                   float* __restrict__ h) {
  __shared__ float als[32][32];
  __shared__ float wols[32][32];
  __shared__ float ys[32][33];
  const int t = threadIdx.x;
  const int r0 = blockIdx.x * 32;
  ((float4*)&als[0][0])[t] = ((const float4*)(attno + (size_t)r0 * 32))[t];
  ((float4*)&wols[0][0])[t] = ((const float4*)wo)[t];
  __syncthreads();
  const int j = t & 31, og = t >> 5;
  float acc[4];
#pragma unroll
  for (int u = 0; u < 4; ++u) acc[u] = bo[j];
  for (int kk = 0; kk < 32; ++kk) {
    const float w = wols[kk][j];
#pragma unroll
    for (int u = 0; u < 4; ++u) acc[u] = fmaf(als[og * 4 + u][kk], w, acc[u]);
  }
#pragma unroll
  for (int u = 0; u < 4; ++u) {
    const int r = og * 4 + u;
    ys[r][j] = h[(size_t)(r0 + r) * 32 + j] + acc[u];
  }
  __syncthreads();
  if (t < 32) {
    float mu = 0.f;
#pragma unroll
    for (int c = 0; c < 32; ++c) mu += ys[t][c];
    mu *= (1.f / 32.f);
    float var = 0.f;
#pragma unroll
    for (int c = 0; c < 32; ++c) {
      const float dd = ys[t][c] - mu;
      var = fmaf(dd, dd, var);
    }
    var *= (1.f / 32.f);
    const float rs = rsqrtf(var + 1e-5f);
#pragma unroll
    for (int c = 0; c < 32; ++c)
      h[(size_t)(r0 + t) * 32 + c] = (ys[t][c] - mu) * rs * g[c] + b[c];
  }
}

// ---------------- FFN + residual + LayerNorm2 ----------------
__global__ __launch_bounds__(256) void ffn_kernel(const float* __restrict__ hin,
                                                  const float* __restrict__ w1,
                                                  const float* __restrict__ b1,
                                                  const float* __restrict__ w2,
                                                  const float* __restrict__ b2,
                                                  const float* __restrict__ g,
                                                  const float* __restrict__ bb,
                                                  float* __restrict__ h) {
  __shared__ float hs[32][32];
  __shared__ float w1s[32][64];
  __shared__ float w2s[64][32];
  __shared__ float mids[32][64];
  __shared__ float ys[32][33];
  const int t = threadIdx.x;
  const int r0 = blockIdx.x * 32;
  ((float4*)&hs[0][0])[t] = ((const float4*)(hin + (size_t)r0 * 32))[t];
#pragma unroll
  for (int i = 0; i < 2; ++i) {
    ((float4*)&w1s[0][0])[t + i * 256] = ((const float4*)w1)[t + i * 256];
    ((float4*)&w2s[0][0])[t + i * 256] = ((const float4*)w2)[t + i * 256];
  }
  __syncthreads();
  {
    const int jm = t & 63, gg = t >> 6;
    float acc[8];
#pragma unroll
    for (int u = 0; u < 8; ++u) acc[u] = b1[jm];
    for (int kk = 0; kk < 32; ++kk) {
      const float w = w1s[kk][jm];
#pragma unroll
      for (int u = 0; u < 8; ++u) acc[u] = fmaf(hs[gg * 8 + u][kk], w, acc[u]);
    }
#pragma unroll
    for (int u = 0; u < 8; ++u) mids[gg * 8 + u][jm] = fmaxf(acc[u], 0.f);
  }
  __syncthreads();
  {
    const int j = t & 31, og = t >> 5;
    float acc[4];
#pragma unroll
    for (int u = 0; u < 4; ++u) acc[u] = b2[j];
    for (int kk = 0; kk < 64; ++kk) {
      const float w = w2s[kk][j];
#pragma unroll
      for (int u = 0; u < 4; ++u) acc[u] = fmaf(mids[og * 4 + u][kk], w, acc[u]);
    }
#pragma unroll
    for (int u = 0; u < 4; ++u) {
      const int r = og * 4 + u;
      ys[r][j] = hs[r][j] + acc[u];
    }
  }
  __syncthreads();
  if (t < 32) {
    float mu = 0.f;
#pragma unroll
    for (int c = 0; c < 32; ++c) mu += ys[t][c];
    mu *= (1.f / 32.f);
    float var = 0.f;
#pragma unroll
    for (int c = 0; c < 32; ++c) {
      const float dd = ys[t][c] - mu;
      var = fmaf(dd, dd, var);
    }
    var *= (1.f / 32.f);
    const float rs = rsqrtf(var + 1e-5f);
#pragma unroll
    for (int c = 0; c < 32; ++c)
      h[(size_t)(r0 + t) * 32 + c] = (ys[t][c] - mu) * rs * g[c] + bb[c];
  }
}

// ---------------- head ----------------
__global__ __launch_bounds__(256) void headp_kernel(const float* __restrict__ h,
                                                    float* __restrict__ partial) {
  __shared__ float red[8][32];
  const int t = threadIdx.x;
  const int c = t & 31, rg = t >> 5;
  const int r0 = blockIdx.x * 64;
  float s = 0.f;
#pragma unroll
  for (int u = 0; u < 8; ++u) s += h[(size_t)(r0 + rg * 8 + u) * 32 + c];
  red[rg][c] = s;
  __syncthreads();
  if (t < 32) {
    float ss = 0.f;
#pragma unroll
    for (int u = 0; u < 8; ++u) ss += red[u][t];
    partial[blockIdx.x * 32 + t] = ss;
  }
}

__global__ __launch_bounds__(64) void headf_kernel(const float* __restrict__ partial,
                                                   const float* __restrict__ w1,
                                                   const float* __restrict__ b1,
                                                   const float* __restrict__ w2,
                                                   const float* __restrict__ b2,
                                                   float* __restrict__ out) {
  __shared__ float mls[32];
  __shared__ float tls[16];
  const int t = threadIdx.x;
  if (t < 32) {
    float s = 0.f;
    for (int bb = 0; bb < 64; ++bb) s += partial[bb * 32 + t];
    mls[t] = s * (1.f / 4096.f);
  }
  __syncthreads();
  if (t < 16) {
    float a = b1[t];
#pragma unroll
    for (int c = 0; c < 32; ++c) a = fmaf(mls[c], w1[c * 16 + t], a);
    tls[t] = tanhf(a);
  }
  __syncthreads();
  if (t == 0) {
    float o = b2[0];
#pragma unroll
    for (int jj = 0; jj < 16; ++jj) o = fmaf(tls[jj], w2[jj], o);
    out[0] = o;
  }
}

extern "C" void kernel_launch(void* const* d_in, const int* in_sizes, int n_in,
                              void* d_out, int out_size, void* d_ws, size_t ws_size,
                              hipStream_t stream) {
  const float* x      = (const float*)d_in[0];
  const float* enc_w1 = (const float*)d_in[1];
  const float* enc_b1 = (const float*)d_in[2];
  const float* enc_w2 = (const float*)d_in[3];
  const float* enc_b2 = (const float*)d_in[4];
  const float* enc_w3 = (const float*)d_in[5];
  const float* enc_b3 = (const float*)d_in[6];
  const float* wq     = (const float*)d_in[7];
  const float* bq     = (const float*)d_in[8];
  const float* wk     = (const float*)d_in[9];
  const float* bk     = (const float*)d_in[10];
  const float* wv     = (const float*)d_in[11];
  const float* bv     = (const float*)d_in[12];
  const float* wo     = (const float*)d_in[13];
  const float* bo     = (const float*)d_in[14];
  const float* ln1_g  = (const float*)d_in[15];
  const float* ln1_b  = (const float*)d_in[16];
  const float* ffn_w1 = (const float*)d_in[17];
  const float* ffn_b1 = (const float*)d_in[18];
  const float* ffn_w2 = (const float*)d_in[19];
  const float* ffn_b2 = (const float*)d_in[20];
  const float* ln2_g  = (const float*)d_in[21];
  const float* ln2_b  = (const float*)d_in[22];
  const float* head_w1 = (const float*)d_in[23];
  const float* head_b1 = (const float*)d_in[24];
  const float* head_w2 = (const float*)d_in[25];
  const float* head_b2 = (const float*)d_in[26];

  float* ws      = (float*)d_ws;
  float* latent  = ws;                    // 131072
  float* normed  = ws + 131072;           // 131072
  float* h       = ws + 262144;           // 131072
  float* q       = ws + 393216;           // 131072
  float* k       = ws + 524288;           // 131072
  float* v       = ws + 655360;           // 131072
  float* attno   = ws + 786432;           // 131072
  float* shreg   = ws + 917504;           // shared region: pool partials, then attn partials
  float* p_acc   = shreg;                 // pool: 8*131072
  float* p_deg   = shreg + 1048576;       // pool: 8*4096
  float* a_acc   = shreg;                 // attn: 8*131072
  float* a_l     = shreg + 1048576;       // attn: 8*16384
  int*   kmax2i  = (int*)(ws + 2097152);  // 8 ints (4 per transformer block)
  float* partial = ws + 2097216;          // 2048

  hipMemsetAsync(kmax2i, 0, 8 * sizeof(int), stream);

  enc_kernel<<<1024, 256, 0, stream>>>(x, enc_w1, enc_b1, enc_w2, enc_b2, enc_w3, enc_b3,
                                       latent, normed);
  pool_kernel<<<dim3(64, JC), 256, 0, stream>>>(normed, latent, p_acc, p_deg);
  pool_combine<<<512, 256, 0, stream>>>(latent, p_acc, p_deg, h);

  for (int blk = 0; blk < 2; ++blk) {
    qkv_kernel<<<128, 256, 0, stream>>>(h, wq + blk * 1024, bq + blk * 32,
                                        wk + blk * 1024, bk + blk * 32,
                                        wv + blk * 1024, bv + blk * 32, q, k, v,
                                        kmax2i + blk * 4);
    attn_kernel<<<dim3(128, JC), 256, 0, stream>>>(q, k, v, kmax2i + blk * 4, a_acc, a_l);
    acombine<<<512, 256, 0, stream>>>(a_acc, a_l, attno);
    oln1_kernel<<<128, 256, 0, stream>>>(attno, wo + blk * 1024, bo + blk * 32,
                                         ln1_g + blk * 32, ln1_b + blk * 32, h);
    ffn_kernel<<<128, 256, 0, stream>>>(h, ffn_w1 + blk * 2048, ffn_b1 + blk * 64,
                                        ffn_w2 + blk * 2048, ffn_b2 + blk * 32,
                                        ln2_g + blk * 32, ln2_b + blk * 32, h);
  }

  headp_kernel<<<64, 256, 0, stream>>>(h, partial);
  headf_kernel<<<1, 64, 0, stream>>>(partial, head_w1, head_b1, head_w2, head_b2, (float*)d_out);
}

// Round 4
// 228.100 us; speedup vs baseline: 1.7062x; 1.7062x over previous
//
#include <hip/hip_runtime.h>
#include <math.h>

#define N 4096
#define DIN 512
#define D 32
#define JC 8

// ---------------- encoder: x[4096,512] -> latent[4096,32] + normed rows, fused ----------------
// R4: exact revert to the R2 version (58.7 us measured). R3's 4-row variant quadrupled w1
// re-reads and was never measured in isolation. enc stays latency-bound (VALUBusy 11%) --
// it is the next target after attn; needs LDS-staged w1, not more blocks.
__global__ __launch_bounds__(256) void enc_kernel(
    const float* __restrict__ x,
    const float* __restrict__ w1, const float* __restrict__ b1,
    const float* __restrict__ w2, const float* __restrict__ b2,
    const float* __restrict__ w3, const float* __restrict__ b3,
    float* __restrict__ latent, float* __restrict__ normed) {
  __shared__ float xs[8][512];
  __shared__ float h1s[8][128];
  __shared__ float h2s[8][64];
  const int t = threadIdx.x;
  const int r0 = blockIdx.x * 8;

  const float4* xg = (const float4*)(x + (size_t)r0 * DIN);
  float4* xl = (float4*)&xs[0][0];
#pragma unroll
  for (int i = 0; i < 4; ++i) xl[t + i * 256] = xg[t + i * 256];
  __syncthreads();

  // layer 1: 512 -> 128, relu. threads: 64 float2-cols x 4 rowgroups (2 rows each)
  {
    const int jc2 = (t & 63) * 2;
    const int rg = t >> 6;
    const int ra = rg * 2, rb = ra + 1;
    float a00 = b1[jc2], a01 = b1[jc2 + 1];
    float a10 = a00, a11 = a01;
#pragma unroll 2
    for (int k = 0; k < 512; k += 4) {
      const float4 xa = *(const float4*)&xs[ra][k];
      const float4 xb = *(const float4*)&xs[rb][k];
      const float2 w0 = *(const float2*)&w1[(size_t)(k + 0) * 128 + jc2];
      const float2 wv1 = *(const float2*)&w1[(size_t)(k + 1) * 128 + jc2];
      const float2 wv2 = *(const float2*)&w1[(size_t)(k + 2) * 128 + jc2];
      const float2 wv3 = *(const float2*)&w1[(size_t)(k + 3) * 128 + jc2];
      a00 = fmaf(xa.x, w0.x, a00);  a01 = fmaf(xa.x, w0.y, a01);
      a10 = fmaf(xb.x, w0.x, a10);  a11 = fmaf(xb.x, w0.y, a11);
      a00 = fmaf(xa.y, wv1.x, a00); a01 = fmaf(xa.y, wv1.y, a01);
      a10 = fmaf(xb.y, wv1.x, a10); a11 = fmaf(xb.y, wv1.y, a11);
      a00 = fmaf(xa.z, wv2.x, a00); a01 = fmaf(xa.z, wv2.y, a01);
      a10 = fmaf(xb.z, wv2.x, a10); a11 = fmaf(xb.z, wv2.y, a11);
      a00 = fmaf(xa.w, wv3.x, a00); a01 = fmaf(xa.w, wv3.y, a01);
      a10 = fmaf(xb.w, wv3.x, a10); a11 = fmaf(xb.w, wv3.y, a11);
    }
    h1s[ra][jc2] = fmaxf(a00, 0.f);
    h1s[ra][jc2 + 1] = fmaxf(a01, 0.f);
    h1s[rb][jc2] = fmaxf(a10, 0.f);
    h1s[rb][jc2 + 1] = fmaxf(a11, 0.f);
  }
  __syncthreads();

  // layer 2: 128 -> 64, relu. threads: 64 cols x 4 rowgroups (2 rows each)
  {
    const int j = t & 63, rg = t >> 6;
    const int ra = rg * 2, rb = ra + 1;
    float a0 = b2[j], a1 = b2[j];
#pragma unroll 4
    for (int k = 0; k < 128; ++k) {
      const float w = w2[k * 64 + j];
      a0 = fmaf(h1s[ra][k], w, a0);
      a1 = fmaf(h1s[rb][k], w, a1);
    }
    h2s[ra][j] = fmaxf(a0, 0.f);
    h2s[rb][j] = fmaxf(a1, 0.f);
  }
  __syncthreads();

  // layer 3: 64 -> 32 + fused row-normalize (shfl reduce over the 32 j-lanes)
  {
    const int j = t & 31, og = t >> 5;  // 8 rows, 1 per group
    float acc = b3[j];
#pragma unroll 4
    for (int k = 0; k < 64; ++k) acc = fmaf(h2s[og][k], w3[k * 32 + j], acc);
    float s2 = acc * acc;
    s2 += __shfl_xor(s2, 1);
    s2 += __shfl_xor(s2, 2);
    s2 += __shfl_xor(s2, 4);
    s2 += __shfl_xor(s2, 8);
    s2 += __shfl_xor(s2, 16);
    const float inv = 1.0f / (sqrtf(s2) + 1e-12f);
    const size_t off = (size_t)(r0 + og) * D + j;
    latent[off] = acc;
    normed[off] = acc * inv;
  }
}

// ---------------- graph pool partials: block (bi, bj) covers 64 i-rows x 512 j ----------------
__global__ __launch_bounds__(256) void pool_kernel(const float* __restrict__ normed,
                                                   const float* __restrict__ latent,
                                                   float* __restrict__ pacc,
                                                   float* __restrict__ pdeg) {
  __shared__ float smem[8192 + 256];
  float* nt = smem;
  float* lt = smem + 4096;
  float* degr = smem + 8192;
  const int t = threadIdx.x;
  const int il = t & 63, g = t >> 6;
  const int i0 = blockIdx.x * 64;
  const int j0 = blockIdx.y * 512;

  float ni[32];
  const float* nrow = normed + (size_t)(i0 + il) * D;
#pragma unroll
  for (int c = 0; c < 32; ++c) ni[c] = nrow[c];

  float acc[32];
#pragma unroll
  for (int c = 0; c < 32; ++c) acc[c] = 0.f;
  float deg = 0.f;

  for (int jt = j0; jt < j0 + 512; jt += 128) {
    __syncthreads();
    const float4* ng = (const float4*)(normed + (size_t)jt * D);
    const float4* lg = (const float4*)(latent + (size_t)jt * D);
    float4* ntl = (float4*)nt;
    float4* ltl = (float4*)lt;
#pragma unroll
    for (int i = 0; i < 4; ++i) {
      ntl[t + i * 256] = ng[t + i * 256];
      ltl[t + i * 256] = lg[t + i * 256];
    }
    __syncthreads();
    for (int jj = g; jj < 128; jj += 4) {
      const float* nr = nt + jj * 32;
      float s = 0.f;
#pragma unroll
      for (int c = 0; c < 32; ++c) s = fmaf(ni[c], nr[c], s);
      if (s >= 0.9f) {
        deg += 1.f;
        const float* lrow = lt + jj * 32;
#pragma unroll
        for (int c = 0; c < 32; ++c) acc[c] += lrow[c];
      }
    }
  }
  __syncthreads();
  float* accr = smem;
#pragma unroll
  for (int c = 0; c < 32; ++c) accr[(g * 64 + il) * 32 + c] = acc[c];
  degr[t] = deg;
  __syncthreads();
  for (int e = t; e < 64 * 32; e += 256) {
    const float s = accr[e] + accr[2048 + e] + accr[4096 + e] + accr[6144 + e];
    pacc[((size_t)blockIdx.y * N + i0 + (e >> 5)) * 32 + (e & 31)] = s;
  }
  if (t < 64) {
    pdeg[(size_t)blockIdx.y * N + i0 + t] = degr[t] + degr[64 + t] + degr[128 + t] + degr[192 + t];
  }
}

// ---------------- combine pool partials -> h = latent + (mask@latent)/deg ----------------
__global__ __launch_bounds__(256) void pool_combine(const float* __restrict__ latent,
                                                    const float* __restrict__ pacc,
                                                    const float* __restrict__ pdeg,
                                                    float* __restrict__ h) {
  const int e = blockIdx.x * 256 + threadIdx.x;
  const int i = e >> 5;
  float s = 0.f, dg = 0.f;
#pragma unroll
  for (int gch = 0; gch < JC; ++gch) {
    s += pacc[(size_t)gch * N * 32 + e];
    dg += pdeg[(size_t)gch * N + i];
  }
  h[e] = latent[e] + s / dg;
}

// ---------------- fused QKV projection (q pre-scaled by log2e/sqrt(8)) + k-norm max ----------------
__global__ __launch_bounds__(256) void qkv_kernel(
    const float* __restrict__ h,
    const float* __restrict__ wq, const float* __restrict__ bq,
    const float* __restrict__ wk, const float* __restrict__ bk,
    const float* __restrict__ wv, const float* __restrict__ bv,
    float* __restrict__ q, float* __restrict__ k, float* __restrict__ v,
    int* __restrict__ kmax2i) {
  __shared__ float hs[32][32];
  __shared__ float wsm[3][32][32];
  __shared__ int kred[4];
  const int t = threadIdx.x;
  const int r0 = blockIdx.x * 32;
  if (t < 4) kred[t] = 0;
  ((float4*)&hs[0][0])[t] = ((const float4*)(h + (size_t)r0 * 32))[t];
  ((float4*)&wsm[0][0][0])[t] = ((const float4*)wq)[t];
  ((float4*)&wsm[1][0][0])[t] = ((const float4*)wk)[t];
  ((float4*)&wsm[2][0][0])[t] = ((const float4*)wv)[t];
  __syncthreads();
  const int j = t & 31, og = t >> 5;
  const int head = j >> 3;
  float aq[4], ak[4], av[4];
#pragma unroll
  for (int u = 0; u < 4; ++u) { aq[u] = bq[j]; ak[u] = bk[j]; av[u] = bv[j]; }
  for (int kk = 0; kk < 32; ++kk) {
    const float wqv = wsm[0][kk][j], wkv = wsm[1][kk][j], wvv = wsm[2][kk][j];
#pragma unroll
    for (int u = 0; u < 4; ++u) {
      const float hh = hs[og * 4 + u][kk];
      aq[u] = fmaf(hh, wqv, aq[u]);
      ak[u] = fmaf(hh, wkv, ak[u]);
      av[u] = fmaf(hh, wvv, av[u]);
    }
  }
  const float scale = 1.4426950408889634f * 0.35355339059327373f;  // log2(e)/sqrt(8)
#pragma unroll
  for (int u = 0; u < 4; ++u) {
    const size_t off = (size_t)(r0 + og * 4 + u) * 32 + j;
    q[off] = aq[u] * scale;
    k[off] = ak[u];
    v[off] = av[u];
  }
  // per-(row,head) ||k8||^2 via shfl over the 8 lanes of this head; block-max; global atomicMax
#pragma unroll
  for (int u = 0; u < 4; ++u) {
    float s2 = ak[u] * ak[u];
    s2 += __shfl_xor(s2, 1);
    s2 += __shfl_xor(s2, 2);
    s2 += __shfl_xor(s2, 4);
    if ((j & 7) == 0) atomicMax(&kred[head], __float_as_int(s2));
  }
  __syncthreads();
  if (t < 4) atomicMax(&kmax2i[t], kred[t]);
}

// ---------------- attention partials: block (rowBlk, jChunk); 64 rows x 512 j ----------------
// R4: back to R2's swizzled-LDS skeleton (R3's no-LDS streamed loads were latency-bound:
// VALUBusy 22%, 126 us). The R2 counters priced the kernel at ~41 us ds_read + ~14 us
// conflicts; LDS reads per THREAD are u-independent, so raising u (q-rows/thread) 2->8
// cuts total LDS wave-traffic 4x (2048 -> 512 blocks): ~10 us ds_read + ~3.4 us conflicts
// vs ~15.5 us VALU floor. Regs ~175 (qa/qb 64 + acc 64 + mneg/l 16 + temps);
// launch_bounds(256,2) -> 2 blocks/CU, spill-free. Per-row FP order identical to R2.
__global__ __launch_bounds__(256, 2) void attn_kernel(const float* __restrict__ q,
                                                      const float* __restrict__ k,
                                                      const float* __restrict__ v,
                                                      const int* __restrict__ kmax2i,
                                                      float* __restrict__ apacc,
                                                      float* __restrict__ apl) {
  __shared__ float4 tiles[1024];  // kls[64*8] | vls[64*8], chunk-XOR swizzled
  float4* kls = tiles;
  float4* vls = tiles + 512;
  const int t = threadIdx.x;
  const int jg = t & 7, head = (t >> 3) & 3, rg = t >> 5;
  const int r0 = blockIdx.x * 64;
  const int j0 = blockIdx.y * (N / JC);

  const float km2 = __int_as_float(kmax2i[head]);

  float4 qa[8], qb[8], accA[8], accB[8];
  float mneg[8], l[8];
#pragma unroll
  for (int u = 0; u < 8; ++u) {
    const float* qr = q + (size_t)(r0 + rg * 8 + u) * 32 + head * 8;
    qa[u] = ((const float4*)qr)[0];
    qb[u] = ((const float4*)qr)[1];
    const float qn2 = qa[u].x * qa[u].x + qa[u].y * qa[u].y + qa[u].z * qa[u].z + qa[u].w * qa[u].w +
                      qb[u].x * qb[u].x + qb[u].y * qb[u].y + qb[u].z * qb[u].z + qb[u].w * qb[u].w;
    mneg[u] = -sqrtf(qn2 * km2);
    l[u] = 0.f;
    accA[u] = make_float4(0.f, 0.f, 0.f, 0.f);
    accB[u] = make_float4(0.f, 0.f, 0.f, 0.f);
  }

  const int h2 = head * 2;
  const int s0 = h2 ^ jg, s1 = (h2 + 1) ^ jg;
  for (int jt = j0; jt < j0 + (N / JC); jt += 64) {
    __syncthreads();
    const float4* kg = (const float4*)(k + (size_t)jt * 32);
    const float4* vg = (const float4*)(v + (size_t)jt * 32);
#pragma unroll
    for (int i = 0; i < 2; ++i) {
      const int gidx = t + i * 256;
      const int r = gidx >> 3, cc = gidx & 7, slot = cc ^ (r & 7);
      kls[r * 8 + slot] = kg[gidx];
      vls[r * 8 + slot] = vg[gidx];
    }
    __syncthreads();
#pragma unroll
    for (int it = 0; it < 8; ++it) {
      const int jj = it * 8 + jg;
      const float4 ka = kls[jj * 8 + s0];
      const float4 kb = kls[jj * 8 + s1];
      const float4 va = vls[jj * 8 + s0];
      const float4 vb = vls[jj * 8 + s1];
#pragma unroll
      for (int u = 0; u < 8; ++u) {
        float s = fmaf(qa[u].x, ka.x, mneg[u]);
        s = fmaf(qa[u].y, ka.y, s);
        s = fmaf(qa[u].z, ka.z, s);
        s = fmaf(qa[u].w, ka.w, s);
        s = fmaf(qb[u].x, kb.x, s);
        s = fmaf(qb[u].y, kb.y, s);
        s = fmaf(qb[u].z, kb.z, s);
        s = fmaf(qb[u].w, kb.w, s);
        const float p = __builtin_amdgcn_exp2f(s);
        l[u] += p;
        accA[u].x = fmaf(p, va.x, accA[u].x);
        accA[u].y = fmaf(p, va.y, accA[u].y);
        accA[u].z = fmaf(p, va.z, accA[u].z);
        accA[u].w = fmaf(p, va.w, accA[u].w);
        accB[u].x = fmaf(p, vb.x, accB[u].x);
        accB[u].y = fmaf(p, vb.y, accB[u].y);
        accB[u].z = fmaf(p, vb.z, accB[u].z);
        accB[u].w = fmaf(p, vb.w, accB[u].w);
      }
    }
  }
  // butterfly-reduce the 8 jg partials (jg = lane bits 0..2); all lanes end with the sum
#pragma unroll
  for (int u = 0; u < 8; ++u) {
#pragma unroll
    for (int m = 1; m <= 4; m <<= 1) {
      accA[u].x += __shfl_xor(accA[u].x, m);
      accA[u].y += __shfl_xor(accA[u].y, m);
      accA[u].z += __shfl_xor(accA[u].z, m);
      accA[u].w += __shfl_xor(accA[u].w, m);
      accB[u].x += __shfl_xor(accB[u].x, m);
      accB[u].y += __shfl_xor(accB[u].y, m);
      accB[u].z += __shfl_xor(accB[u].z, m);
      accB[u].w += __shfl_xor(accB[u].w, m);
      l[u] += __shfl_xor(l[u], m);
    }
  }
  if (jg == 0) {
#pragma unroll
    for (int u = 0; u < 8; ++u) {
      const int row = r0 + rg * 8 + u;
      float* ap = apacc + (size_t)blockIdx.y * N * 32 + (size_t)row * 32 + head * 8;
      ((float4*)ap)[0] = accA[u];
      ((float4*)ap)[1] = accB[u];
      apl[(size_t)blockIdx.y * N * 4 + (size_t)row * 4 + head] = l[u];
    }
  }
}

// ---------------- combine attention partials ----------------
__global__ __launch_bounds__(256) void acombine(const float* __restrict__ apacc,
                                                const float* __restrict__ apl,
                                                float* __restrict__ attno) {
  const int e = blockIdx.x * 256 + threadIdx.x;  // < N*32
  const int row = e >> 5;
  const int hh = (e >> 3) & 3;
  float L = 0.f, S = 0.f;
#pragma unroll
  for (int jc = 0; jc < JC; ++jc) {
    L += apl[(size_t)jc * N * 4 + row * 4 + hh];
    S += apacc[(size_t)jc * N * 32 + e];
  }
  attno[e] = S / L;
}

// ---------------- O-projection + residual + LayerNorm1 ----------------
__global__ __launch_bounds__(256) void oln1_kernel(const float* __restrict__ attno,
                                                   const float* __restrict__ wo,
                                                   const float* __restrict__ bo,
                                                   const float* __restrict__ g,
                                                   const float* __restrict__ b,
                                                   float* __restrict__ h) {
  __shared__ float als[32][32];
  __shared__ float wols[32][32];
  __shared__ float ys[32][33];
  const int t = threadIdx.x;
  const int r0 = blockIdx.x * 32;
  ((float4*)&als[0][0])[t] = ((const float4*)(attno + (size_t)r0 * 32))[t];
  ((float4*)&wols[0][0])[t] = ((const float4*)wo)[t];
  __syncthreads();
  const int j = t & 31, og = t >> 5;
  float acc[4];
#pragma unroll
  for (int u = 0; u < 4; ++u) acc[u] = bo[j];
  for (int kk = 0; kk < 32; ++kk) {
    const float w = wols[kk][j];
#pragma unroll
    for (int u = 0; u < 4; ++u) acc[u] = fmaf(als[og * 4 + u][kk], w, acc[u]);
  }
#pragma unroll
  for (int u = 0; u < 4; ++u) {
    const int r = og * 4 + u;
    ys[r][j] = h[(size_t)(r0 + r) * 32 + j] + acc[u];
  }
  __syncthreads();
  if (t < 32) {
    float mu = 0.f;
#pragma unroll
    for (int c = 0; c < 32; ++c) mu += ys[t][c];
    mu *= (1.f / 32.f);
    float var = 0.f;
#pragma unroll
    for (int c = 0; c < 32; ++c) {
      const float dd = ys[t][c] - mu;
      var = fmaf(dd, dd, var);
    }
    var *= (1.f / 32.f);
    const float rs = rsqrtf(var + 1e-5f);
#pragma unroll
    for (int c = 0; c < 32; ++c)
      h[(size_t)(r0 + t) * 32 + c] = (ys[t][c] - mu) * rs * g[c] + b[c];
  }
}

// ---------------- FFN + residual + LayerNorm2 ----------------
__global__ __launch_bounds__(256) void ffn_kernel(const float* __restrict__ hin,
                                                  const float* __restrict__ w1,
                                                  const float* __restrict__ b1,
                                                  const float* __restrict__ w2,
                                                  const float* __restrict__ b2,
                                                  const float* __restrict__ g,
                                                  const float* __restrict__ bb,
                                                  float* __restrict__ h) {
  __shared__ float hs[32][32];
  __shared__ float w1s[32][64];
  __shared__ float w2s[64][32];
  __shared__ float mids[32][64];
  __shared__ float ys[32][33];
  const int t = threadIdx.x;
  const int r0 = blockIdx.x * 32;
  ((float4*)&hs[0][0])[t] = ((const float4*)(hin + (size_t)r0 * 32))[t];
#pragma unroll
  for (int i = 0; i < 2; ++i) {
    ((float4*)&w1s[0][0])[t + i * 256] = ((const float4*)w1)[t + i * 256];
    ((float4*)&w2s[0][0])[t + i * 256] = ((const float4*)w2)[t + i * 256];
  }
  __syncthreads();
  {
    const int jm = t & 63, gg = t >> 6;
    float acc[8];
#pragma unroll
    for (int u = 0; u < 8; ++u) acc[u] = b1[jm];
    for (int kk = 0; kk < 32; ++kk) {
      const float w = w1s[kk][jm];
#pragma unroll
      for (int u = 0; u < 8; ++u) acc[u] = fmaf(hs[gg * 8 + u][kk], w, acc[u]);
    }
#pragma unroll
    for (int u = 0; u < 8; ++u) mids[gg * 8 + u][jm] = fmaxf(acc[u], 0.f);
  }
  __syncthreads();
  {
    const int j = t & 31, og = t >> 5;
    float acc[4];
#pragma unroll
    for (int u = 0; u < 4; ++u) acc[u] = b2[j];
    for (int kk = 0; kk < 64; ++kk) {
      const float w = w2s[kk][j];
#pragma unroll
      for (int u = 0; u < 4; ++u) acc[u] = fmaf(mids[og * 4 + u][kk], w, acc[u]);
    }
#pragma unroll
    for (int u = 0; u < 4; ++u) {
      const int r = og * 4 + u;
      ys[r][j] = hs[r][j] + acc[u];
    }
  }
  __syncthreads();
  if (t < 32) {
    float mu = 0.f;
#pragma unroll
    for (int c = 0; c < 32; ++c) mu += ys[t][c];
    mu *= (1.f / 32.f);
    float var = 0.f;
#pragma unroll
    for (int c = 0; c < 32; ++c) {
      const float dd = ys[t][c] - mu;
      var = fmaf(dd, dd, var);
    }
    var *= (1.f / 32.f);
    const float rs = rsqrtf(var + 1e-5f);
#pragma unroll
    for (int c = 0; c < 32; ++c)
      h[(size_t)(r0 + t) * 32 + c] = (ys[t][c] - mu) * rs * g[c] + bb[c];
  }
}

// ---------------- head ----------------
__global__ __launch_bounds__(256) void headp_kernel(const float* __restrict__ h,
                                                    float* __restrict__ partial) {
  __shared__ float red[8][32];
  const int t = threadIdx.x;
  const int c = t & 31, rg = t >> 5;
  const int r0 = blockIdx.x * 64;
  float s = 0.f;
#pragma unroll
  for (int u = 0; u < 8; ++u) s += h[(size_t)(r0 + rg * 8 + u) * 32 + c];
  red[rg][c] = s;
  __syncthreads();
  if (t < 32) {
    float ss = 0.f;
#pragma unroll
    for (int u = 0; u < 8; ++u) ss += red[u][t];
    partial[blockIdx.x * 32 + t] = ss;
  }
}

__global__ __launch_bounds__(64) void headf_kernel(const float* __restrict__ partial,
                                                   const float* __restrict__ w1,
                                                   const float* __restrict__ b1,
                                                   const float* __restrict__ w2,
                                                   const float* __restrict__ b2,
                                                   float* __restrict__ out) {
  __shared__ float mls[32];
  __shared__ float tls[16];
  const int t = threadIdx.x;
  if (t < 32) {
    float s = 0.f;
    for (int bb = 0; bb < 64; ++bb) s += partial[bb * 32 + t];
    mls[t] = s * (1.f / 4096.f);
  }
  __syncthreads();
  if (t < 16) {
    float a = b1[t];
#pragma unroll
    for (int c = 0; c < 32; ++c) a = fmaf(mls[c], w1[c * 16 + t], a);
    tls[t] = tanhf(a);
  }
  __syncthreads();
  if (t == 0) {
    float o = b2[0];
#pragma unroll
    for (int jj = 0; jj < 16; ++jj) o = fmaf(tls[jj], w2[jj], o);
    out[0] = o;
  }
}

extern "C" void kernel_launch(void* const* d_in, const int* in_sizes, int n_in,
                              void* d_out, int out_size, void* d_ws, size_t ws_size,
                              hipStream_t stream) {
  const float* x      = (const float*)d_in[0];
  const float* enc_w1 = (const float*)d_in[1];
  const float* enc_b1 = (const float*)d_in[2];
  const float* enc_w2 = (const float*)d_in[3];
  const float* enc_b2 = (const float*)d_in[4];
  const float* enc_w3 = (const float*)d_in[5];
  const float* enc_b3 = (const float*)d_in[6];
  const float* wq     = (const float*)d_in[7];
  const float* bq     = (const float*)d_in[8];
  const float* wk     = (const float*)d_in[9];
  const float* bk     = (const float*)d_in[10];
  const float* wv     = (const float*)d_in[11];
  const float* bv     = (const float*)d_in[12];
  const float* wo     = (const float*)d_in[13];
  const float* bo     = (const float*)d_in[14];
  const float* ln1_g  = (const float*)d_in[15];
  const float* ln1_b  = (const float*)d_in[16];
  const float* ffn_w1 = (const float*)d_in[17];
  const float* ffn_b1 = (const float*)d_in[18];
  const float* ffn_w2 = (const float*)d_in[19];
  const float* ffn_b2 = (const float*)d_in[20];
  const float* ln2_g  = (const float*)d_in[21];
  const float* ln2_b  = (const float*)d_in[22];
  const float* head_w1 = (const float*)d_in[23];
  const float* head_b1 = (const float*)d_in[24];
  const float* head_w2 = (const float*)d_in[25];
  const float* head_b2 = (const float*)d_in[26];

  float* ws      = (float*)d_ws;
  float* latent  = ws;                    // 131072
  float* normed  = ws + 131072;           // 131072
  float* h       = ws + 262144;           // 131072
  float* q       = ws + 393216;           // 131072
  float* k       = ws + 524288;           // 131072
  float* v       = ws + 655360;           // 131072
  float* attno   = ws + 786432;           // 131072
  float* shreg   = ws + 917504;           // shared region: pool partials, then attn partials
  float* p_acc   = shreg;                 // pool: 8*131072
  float* p_deg   = shreg + 1048576;       // pool: 8*4096
  float* a_acc   = shreg;                 // attn: 8*131072
  float* a_l     = shreg + 1048576;       // attn: 8*16384
  int*   kmax2i  = (int*)(ws + 2097152);  // 8 ints (4 per transformer block)
  float* partial = ws + 2097216;          // 2048

  hipMemsetAsync(kmax2i, 0, 8 * sizeof(int), stream);

  enc_kernel<<<512, 256, 0, stream>>>(x, enc_w1, enc_b1, enc_w2, enc_b2, enc_w3, enc_b3,
                                      latent, normed);
  pool_kernel<<<dim3(64, JC), 256, 0, stream>>>(normed, latent, p_acc, p_deg);
  pool_combine<<<512, 256, 0, stream>>>(latent, p_acc, p_deg, h);

  for (int blk = 0; blk < 2; ++blk) {
    qkv_kernel<<<128, 256, 0, stream>>>(h, wq + blk * 1024, bq + blk * 32,
                                        wk + blk * 1024, bk + blk * 32,
                                        wv + blk * 1024, bv + blk * 32, q, k, v,
                                        kmax2i + blk * 4);
    attn_kernel<<<dim3(64, JC), 256, 0, stream>>>(q, k, v, kmax2i + blk * 4, a_acc, a_l);
    acombine<<<512, 256, 0, stream>>>(a_acc, a_l, attno);
    oln1_kernel<<<128, 256, 0, stream>>>(attno, wo + blk * 1024, bo + blk * 32,
                                         ln1_g + blk * 32, ln1_b + blk * 32, h);
    ffn_kernel<<<128, 256, 0, stream>>>(h, ffn_w1 + blk * 2048, ffn_b1 + blk * 64,
                                        ffn_w2 + blk * 2048, ffn_b2 + blk * 32,
                                        ln2_g + blk * 32, ln2_b + blk * 32, h);
  }

  headp_kernel<<<64, 256, 0, stream>>>(h, partial);
  headf_kernel<<<1, 64, 0, stream>>>(partial, head_w1, head_b1, head_w2, head_b2, (float*)d_out);
}

// Round 5
// 199.880 us; speedup vs baseline: 1.9471x; 1.1412x over previous
//
#include <hip/hip_runtime.h>
#include <math.h>

#define N 4096
#define DIN 512
#define D 32
#define JC 8

// ---------------- encoder: x[4096,512] -> latent[4096,32] + normed rows, fused ----------------
// R5: layer-1 was L2-latency-bound (VALUBusy 11%: only 8 w1 loads in flight over a
// 512-deep serial k-loop). Explicit 4-stage ring prefetch (16 k-steps ahead, consume-then-
// reload named regs -> no runtime indexing/scratch) keeps ~16 loads in flight; w2/w3 are
// LDS-staged at block start (kills 4x-duplicated scalar L2 reads in layers 2/3; the
// existing post-layer1 barrier covers the staging). LDS 62 KB -> 2 blocks/CU.
// Per-accumulator FP order unchanged (k ascending) -> bit-identical.
__global__ __launch_bounds__(256) void enc_kernel(
    const float* __restrict__ x,
    const float* __restrict__ w1, const float* __restrict__ b1,
    const float* __restrict__ w2, const float* __restrict__ b2,
    const float* __restrict__ w3, const float* __restrict__ b3,
    float* __restrict__ latent, float* __restrict__ normed) {
  __shared__ float xs[8][512];
  __shared__ float h1s[8][128];
  __shared__ float h2s[8][64];
  __shared__ float w2s[128][64];
  __shared__ float w3s[64][32];
  const int t = threadIdx.x;
  const int r0 = blockIdx.x * 8;

  // stage x rows + w2 + w3 into LDS (one barrier covers all)
  const float4* xg = (const float4*)(x + (size_t)r0 * DIN);
  float4* xl = (float4*)&xs[0][0];
#pragma unroll
  for (int i = 0; i < 4; ++i) xl[t + i * 256] = xg[t + i * 256];
  float4* w2l = (float4*)&w2s[0][0];
  const float4* w2g = (const float4*)w2;
#pragma unroll
  for (int i = 0; i < 8; ++i) w2l[t + i * 256] = w2g[t + i * 256];
  float4* w3l = (float4*)&w3s[0][0];
  const float4* w3g = (const float4*)w3;
#pragma unroll
  for (int i = 0; i < 2; ++i) w3l[t + i * 256] = w3g[t + i * 256];
  __syncthreads();

  // layer 1: 512 -> 128, relu. threads: 64 float2-cols x 4 rowgroups (2 rows each)
  {
    const int jc2 = (t & 63) * 2;
    const int rg = t >> 6;
    const int ra = rg * 2, rb = ra + 1;
    float a00 = b1[jc2], a01 = b1[jc2 + 1];
    float a10 = a00, a11 = a01;
    const float* wp = w1 + jc2;

#define ENC_LD4(P0, P1, P2, P3, KB)                         \
    P0 = *(const float2*)&wp[(size_t)(KB) * 128];           \
    P1 = *(const float2*)&wp[(size_t)((KB) + 1) * 128];     \
    P2 = *(const float2*)&wp[(size_t)((KB) + 2) * 128];     \
    P3 = *(const float2*)&wp[(size_t)((KB) + 3) * 128];

#define ENC_L1_STEP(W0, WA, WB, WC, KB)                               \
    {                                                                 \
      const float4 xa = *(const float4*)&xs[ra][KB];                  \
      const float4 xb = *(const float4*)&xs[rb][KB];                  \
      a00 = fmaf(xa.x, W0.x, a00);  a01 = fmaf(xa.x, W0.y, a01);      \
      a10 = fmaf(xb.x, W0.x, a10);  a11 = fmaf(xb.x, W0.y, a11);      \
      a00 = fmaf(xa.y, WA.x, a00);  a01 = fmaf(xa.y, WA.y, a01);      \
      a10 = fmaf(xb.y, WA.x, a10);  a11 = fmaf(xb.y, WA.y, a11);      \
      a00 = fmaf(xa.z, WB.x, a00);  a01 = fmaf(xa.z, WB.y, a01);      \
      a10 = fmaf(xb.z, WB.x, a10);  a11 = fmaf(xb.z, WB.y, a11);      \
      a00 = fmaf(xa.w, WC.x, a00);  a01 = fmaf(xa.w, WC.y, a01);      \
      a10 = fmaf(xb.w, WC.x, a10);  a11 = fmaf(xb.w, WC.y, a11);      \
    }

    float2 A0, A1, A2, A3, B0, B1, B2, B3, C0, C1, C2, C3, D0, D1, D2, D3;
    ENC_LD4(A0, A1, A2, A3, 0)
    ENC_LD4(B0, B1, B2, B3, 4)
    ENC_LD4(C0, C1, C2, C3, 8)
    ENC_LD4(D0, D1, D2, D3, 12)
    for (int k = 0; k < 512; k += 16) {
      ENC_L1_STEP(A0, A1, A2, A3, k + 0);
      if (k + 16 < 512) { ENC_LD4(A0, A1, A2, A3, k + 16) }
      ENC_L1_STEP(B0, B1, B2, B3, k + 4);
      if (k + 20 < 512) { ENC_LD4(B0, B1, B2, B3, k + 20) }
      ENC_L1_STEP(C0, C1, C2, C3, k + 8);
      if (k + 24 < 512) { ENC_LD4(C0, C1, C2, C3, k + 24) }
      ENC_L1_STEP(D0, D1, D2, D3, k + 12);
      if (k + 28 < 512) { ENC_LD4(D0, D1, D2, D3, k + 28) }
    }
#undef ENC_L1_STEP
#undef ENC_LD4
    h1s[ra][jc2] = fmaxf(a00, 0.f);
    h1s[ra][jc2 + 1] = fmaxf(a01, 0.f);
    h1s[rb][jc2] = fmaxf(a10, 0.f);
    h1s[rb][jc2 + 1] = fmaxf(a11, 0.f);
  }
  __syncthreads();

  // layer 2: 128 -> 64, relu. weights from LDS (w2s), h1 broadcast reads
  {
    const int j = t & 63, rg = t >> 6;
    const int ra = rg * 2, rb = ra + 1;
    float a0 = b2[j], a1 = b2[j];
#pragma unroll 8
    for (int kk = 0; kk < 128; ++kk) {
      const float w = w2s[kk][j];
      a0 = fmaf(h1s[ra][kk], w, a0);
      a1 = fmaf(h1s[rb][kk], w, a1);
    }
    h2s[ra][j] = fmaxf(a0, 0.f);
    h2s[rb][j] = fmaxf(a1, 0.f);
  }
  __syncthreads();

  // layer 3: 64 -> 32 + fused row-normalize (shfl reduce over the 32 j-lanes)
  {
    const int j = t & 31, og = t >> 5;  // 8 rows, 1 per group
    float acc = b3[j];
#pragma unroll 8
    for (int kk = 0; kk < 64; ++kk) acc = fmaf(h2s[og][kk], w3s[kk][j], acc);
    float s2 = acc * acc;
    s2 += __shfl_xor(s2, 1);
    s2 += __shfl_xor(s2, 2);
    s2 += __shfl_xor(s2, 4);
    s2 += __shfl_xor(s2, 8);
    s2 += __shfl_xor(s2, 16);
    const float inv = 1.0f / (sqrtf(s2) + 1e-12f);
    const size_t off = (size_t)(r0 + og) * D + j;
    latent[off] = acc;
    normed[off] = acc * inv;
  }
}

// ---------------- graph pool partials: block (bi, bj) covers 64 i-rows x 512 j ----------------
__global__ __launch_bounds__(256) void pool_kernel(const float* __restrict__ normed,
                                                   const float* __restrict__ latent,
                                                   float* __restrict__ pacc,
                                                   float* __restrict__ pdeg) {
  __shared__ float smem[8192 + 256];
  float* nt = smem;
  float* lt = smem + 4096;
  float* degr = smem + 8192;
  const int t = threadIdx.x;
  const int il = t & 63, g = t >> 6;
  const int i0 = blockIdx.x * 64;
  const int j0 = blockIdx.y * 512;

  float ni[32];
  const float* nrow = normed + (size_t)(i0 + il) * D;
#pragma unroll
  for (int c = 0; c < 32; ++c) ni[c] = nrow[c];

  float acc[32];
#pragma unroll
  for (int c = 0; c < 32; ++c) acc[c] = 0.f;
  float deg = 0.f;

  for (int jt = j0; jt < j0 + 512; jt += 128) {
    __syncthreads();
    const float4* ng = (const float4*)(normed + (size_t)jt * D);
    const float4* lg = (const float4*)(latent + (size_t)jt * D);
    float4* ntl = (float4*)nt;
    float4* ltl = (float4*)lt;
#pragma unroll
    for (int i = 0; i < 4; ++i) {
      ntl[t + i * 256] = ng[t + i * 256];
      ltl[t + i * 256] = lg[t + i * 256];
    }
    __syncthreads();
    for (int jj = g; jj < 128; jj += 4) {
      const float* nr = nt + jj * 32;
      float s = 0.f;
#pragma unroll
      for (int c = 0; c < 32; ++c) s = fmaf(ni[c], nr[c], s);
      if (s >= 0.9f) {
        deg += 1.f;
        const float* lrow = lt + jj * 32;
#pragma unroll
        for (int c = 0; c < 32; ++c) acc[c] += lrow[c];
      }
    }
  }
  __syncthreads();
  float* accr = smem;
#pragma unroll
  for (int c = 0; c < 32; ++c) accr[(g * 64 + il) * 32 + c] = acc[c];
  degr[t] = deg;
  __syncthreads();
  for (int e = t; e < 64 * 32; e += 256) {
    const float s = accr[e] + accr[2048 + e] + accr[4096 + e] + accr[6144 + e];
    pacc[((size_t)blockIdx.y * N + i0 + (e >> 5)) * 32 + (e & 31)] = s;
  }
  if (t < 64) {
    pdeg[(size_t)blockIdx.y * N + i0 + t] = degr[t] + degr[64 + t] + degr[128 + t] + degr[192 + t];
  }
}

// ---------------- combine pool partials -> h = latent + (mask@latent)/deg ----------------
__global__ __launch_bounds__(256) void pool_combine(const float* __restrict__ latent,
                                                    const float* __restrict__ pacc,
                                                    const float* __restrict__ pdeg,
                                                    float* __restrict__ h) {
  const int e = blockIdx.x * 256 + threadIdx.x;
  const int i = e >> 5;
  float s = 0.f, dg = 0.f;
#pragma unroll
  for (int gch = 0; gch < JC; ++gch) {
    s += pacc[(size_t)gch * N * 32 + e];
    dg += pdeg[(size_t)gch * N + i];
  }
  h[e] = latent[e] + s / dg;
}

// ---------------- fused QKV projection (q pre-scaled by log2e/sqrt(8)) + k-norm max ----------------
__global__ __launch_bounds__(256) void qkv_kernel(
    const float* __restrict__ h,
    const float* __restrict__ wq, const float* __restrict__ bq,
    const float* __restrict__ wk, const float* __restrict__ bk,
    const float* __restrict__ wv, const float* __restrict__ bv,
    float* __restrict__ q, float* __restrict__ k, float* __restrict__ v,
    int* __restrict__ kmax2i) {
  __shared__ float hs[32][32];
  __shared__ float wsm[3][32][32];
  __shared__ int kred[4];
  const int t = threadIdx.x;
  const int r0 = blockIdx.x * 32;
  if (t < 4) kred[t] = 0;
  ((float4*)&hs[0][0])[t] = ((const float4*)(h + (size_t)r0 * 32))[t];
  ((float4*)&wsm[0][0][0])[t] = ((const float4*)wq)[t];
  ((float4*)&wsm[1][0][0])[t] = ((const float4*)wk)[t];
  ((float4*)&wsm[2][0][0])[t] = ((const float4*)wv)[t];
  __syncthreads();
  const int j = t & 31, og = t >> 5;
  const int head = j >> 3;
  float aq[4], ak[4], av[4];
#pragma unroll
  for (int u = 0; u < 4; ++u) { aq[u] = bq[j]; ak[u] = bk[j]; av[u] = bv[j]; }
  for (int kk = 0; kk < 32; ++kk) {
    const float wqv = wsm[0][kk][j], wkv = wsm[1][kk][j], wvv = wsm[2][kk][j];
#pragma unroll
    for (int u = 0; u < 4; ++u) {
      const float hh = hs[og * 4 + u][kk];
      aq[u] = fmaf(hh, wqv, aq[u]);
      ak[u] = fmaf(hh, wkv, ak[u]);
      av[u] = fmaf(hh, wvv, av[u]);
    }
  }
  const float scale = 1.4426950408889634f * 0.35355339059327373f;  // log2(e)/sqrt(8)
#pragma unroll
  for (int u = 0; u < 4; ++u) {
    const size_t off = (size_t)(r0 + og * 4 + u) * 32 + j;
    q[off] = aq[u] * scale;
    k[off] = ak[u];
    v[off] = av[u];
  }
  // per-(row,head) ||k8||^2 via shfl over the 8 lanes of this head; block-max; global atomicMax
#pragma unroll
  for (int u = 0; u < 4; ++u) {
    float s2 = ak[u] * ak[u];
    s2 += __shfl_xor(s2, 1);
    s2 += __shfl_xor(s2, 2);
    s2 += __shfl_xor(s2, 4);
    if ((j & 7) == 0) atomicMax(&kred[head], __float_as_int(s2));
  }
  __syncthreads();
  if (t < 4) atomicMax(&kmax2i[t], kred[t]);
}

// ---------------- attention partials: block (rowBlk, jChunk); 64 rows x 512 j ----------------
// R5: same u=8 structure as R4, with the spill fixed. R4 spilled (~40 MB scratch traffic,
// VGPR=128): persistent state ~144 regs + full unroll of the 8-step it-loop hoisting up to
// 32 float4 LDS loads -> peak ~270, and the allocator stuck to its 128-reg/4-wave bucket.
// Fix: amdgpu_waves_per_eu(2,2) pins the occupancy target to 2 waves/EU (256-reg budget;
// even 256 regs still leaves 2 blocks/CU), and #pragma unroll 2 on the it-loop bounds
// hoisted loads to ~32 regs. No math/order change.
__global__ __launch_bounds__(256) __attribute__((amdgpu_waves_per_eu(2, 2)))
void attn_kernel(const float* __restrict__ q,
                 const float* __restrict__ k,
                 const float* __restrict__ v,
                 const int* __restrict__ kmax2i,
                 float* __restrict__ apacc,
                 float* __restrict__ apl) {
  __shared__ float4 tiles[1024];  // kls[64*8] | vls[64*8], chunk-XOR swizzled
  float4* kls = tiles;
  float4* vls = tiles + 512;
  const int t = threadIdx.x;
  const int jg = t & 7, head = (t >> 3) & 3, rg = t >> 5;
  const int r0 = blockIdx.x * 64;
  const int j0 = blockIdx.y * (N / JC);

  const float km2 = __int_as_float(kmax2i[head]);

  float4 qa[8], qb[8], accA[8], accB[8];
  float mneg[8], l[8];
#pragma unroll
  for (int u = 0; u < 8; ++u) {
    const float* qr = q + (size_t)(r0 + rg * 8 + u) * 32 + head * 8;
    qa[u] = ((const float4*)qr)[0];
    qb[u] = ((const float4*)qr)[1];
    const float qn2 = qa[u].x * qa[u].x + qa[u].y * qa[u].y + qa[u].z * qa[u].z + qa[u].w * qa[u].w +
                      qb[u].x * qb[u].x + qb[u].y * qb[u].y + qb[u].z * qb[u].z + qb[u].w * qb[u].w;
    mneg[u] = -sqrtf(qn2 * km2);
    l[u] = 0.f;
    accA[u] = make_float4(0.f, 0.f, 0.f, 0.f);
    accB[u] = make_float4(0.f, 0.f, 0.f, 0.f);
  }

  const int h2 = head * 2;
  const int s0 = h2 ^ jg, s1 = (h2 + 1) ^ jg;
  for (int jt = j0; jt < j0 + (N / JC); jt += 64) {
    __syncthreads();
    const float4* kg = (const float4*)(k + (size_t)jt * 32);
    const float4* vg = (const float4*)(v + (size_t)jt * 32);
#pragma unroll
    for (int i = 0; i < 2; ++i) {
      const int gidx = t + i * 256;
      const int r = gidx >> 3, cc = gidx & 7, slot = cc ^ (r & 7);
      kls[r * 8 + slot] = kg[gidx];
      vls[r * 8 + slot] = vg[gidx];
    }
    __syncthreads();
#pragma unroll 2
    for (int it = 0; it < 8; ++it) {
      const int jj = it * 8 + jg;
      const float4 ka = kls[jj * 8 + s0];
      const float4 kb = kls[jj * 8 + s1];
      const float4 va = vls[jj * 8 + s0];
      const float4 vb = vls[jj * 8 + s1];
#pragma unroll
      for (int u = 0; u < 8; ++u) {
        float s = fmaf(qa[u].x, ka.x, mneg[u]);
        s = fmaf(qa[u].y, ka.y, s);
        s = fmaf(qa[u].z, ka.z, s);
        s = fmaf(qa[u].w, ka.w, s);
        s = fmaf(qb[u].x, kb.x, s);
        s = fmaf(qb[u].y, kb.y, s);
        s = fmaf(qb[u].z, kb.z, s);
        s = fmaf(qb[u].w, kb.w, s);
        const float p = __builtin_amdgcn_exp2f(s);
        l[u] += p;
        accA[u].x = fmaf(p, va.x, accA[u].x);
        accA[u].y = fmaf(p, va.y, accA[u].y);
        accA[u].z = fmaf(p, va.z, accA[u].z);
        accA[u].w = fmaf(p, va.w, accA[u].w);
        accB[u].x = fmaf(p, vb.x, accB[u].x);
        accB[u].y = fmaf(p, vb.y, accB[u].y);
        accB[u].z = fmaf(p, vb.z, accB[u].z);
        accB[u].w = fmaf(p, vb.w, accB[u].w);
      }
    }
  }
  // butterfly-reduce the 8 jg partials (jg = lane bits 0..2); all lanes end with the sum
#pragma unroll
  for (int u = 0; u < 8; ++u) {
#pragma unroll
    for (int m = 1; m <= 4; m <<= 1) {
      accA[u].x += __shfl_xor(accA[u].x, m);
      accA[u].y += __shfl_xor(accA[u].y, m);
      accA[u].z += __shfl_xor(accA[u].z, m);
      accA[u].w += __shfl_xor(accA[u].w, m);
      accB[u].x += __shfl_xor(accB[u].x, m);
      accB[u].y += __shfl_xor(accB[u].y, m);
      accB[u].z += __shfl_xor(accB[u].z, m);
      accB[u].w += __shfl_xor(accB[u].w, m);
      l[u] += __shfl_xor(l[u], m);
    }
  }
  if (jg == 0) {
#pragma unroll
    for (int u = 0; u < 8; ++u) {
      const int row = r0 + rg * 8 + u;
      float* ap = apacc + (size_t)blockIdx.y * N * 32 + (size_t)row * 32 + head * 8;
      ((float4*)ap)[0] = accA[u];
      ((float4*)ap)[1] = accB[u];
      apl[(size_t)blockIdx.y * N * 4 + (size_t)row * 4 + head] = l[u];
    }
  }
}

// ---------------- combine attention partials ----------------
__global__ __launch_bounds__(256) void acombine(const float* __restrict__ apacc,
                                                const float* __restrict__ apl,
                                                float* __restrict__ attno) {
  const int e = blockIdx.x * 256 + threadIdx.x;  // < N*32
  const int row = e >> 5;
  const int hh = (e >> 3) & 3;
  float L = 0.f, S = 0.f;
#pragma unroll
  for (int jc = 0; jc < JC; ++jc) {
    L += apl[(size_t)jc * N * 4 + row * 4 + hh];
    S += apacc[(size_t)jc * N * 32 + e];
  }
  attno[e] = S / L;
}

// ---------------- O-projection + residual + LayerNorm1 ----------------
__global__ __launch_bounds__(256) void oln1_kernel(const float* __restrict__ attno,
                                                   const float* __restrict__ wo,
                                                   const float* __restrict__ bo,
                                                   const float* __restrict__ g,
                                                   const float* __restrict__ b,
                                                   float* __restrict__ h) {
  __shared__ float als[32][32];
  __shared__ float wols[32][32];
  __shared__ float ys[32][33];
  const int t = threadIdx.x;
  const int r0 = blockIdx.x * 32;
  ((float4*)&als[0][0])[t] = ((const float4*)(attno + (size_t)r0 * 32))[t];
  ((float4*)&wols[0][0])[t] = ((const float4*)wo)[t];
  __syncthreads();
  const int j = t & 31, og = t >> 5;
  float acc[4];
#pragma unroll
  for (int u = 0; u < 4; ++u) acc[u] = bo[j];
  for (int kk = 0; kk < 32; ++kk) {
    const float w = wols[kk][j];
#pragma unroll
    for (int u = 0; u < 4; ++u) acc[u] = fmaf(als[og * 4 + u][kk], w, acc[u]);
  }
#pragma unroll
  for (int u = 0; u < 4; ++u) {
    const int r = og * 4 + u;
    ys[r][j] = h[(size_t)(r0 + r) * 32 + j] + acc[u];
  }
  __syncthreads();
  if (t < 32) {
    float mu = 0.f;
#pragma unroll
    for (int c = 0; c < 32; ++c) mu += ys[t][c];
    mu *= (1.f / 32.f);
    float var = 0.f;
#pragma unroll
    for (int c = 0; c < 32; ++c) {
      const float dd = ys[t][c] - mu;
      var = fmaf(dd, dd, var);
    }
    var *= (1.f / 32.f);
    const float rs = rsqrtf(var + 1e-5f);
#pragma unroll
    for (int c = 0; c < 32; ++c)
      h[(size_t)(r0 + t) * 32 + c] = (ys[t][c] - mu) * rs * g[c] + b[c];
  }
}

// ---------------- FFN + residual + LayerNorm2 ----------------
__global__ __launch_bounds__(256) void ffn_kernel(const float* __restrict__ hin,
                                                  const float* __restrict__ w1,
                                                  const float* __restrict__ b1,
                                                  const float* __restrict__ w2,
                                                  const float* __restrict__ b2,
                                                  const float* __restrict__ g,
                                                  const float* __restrict__ bb,
                                                  float* __restrict__ h) {
  __shared__ float hs[32][32];
  __shared__ float w1s[32][64];
  __shared__ float w2s[64][32];
  __shared__ float mids[32][64];
  __shared__ float ys[32][33];
  const int t = threadIdx.x;
  const int r0 = blockIdx.x * 32;
  ((float4*)&hs[0][0])[t] = ((const float4*)(hin + (size_t)r0 * 32))[t];
#pragma unroll
  for (int i = 0; i < 2; ++i) {
    ((float4*)&w1s[0][0])[t + i * 256] = ((const float4*)w1)[t + i * 256];
    ((float4*)&w2s[0][0])[t + i * 256] = ((const float4*)w2)[t + i * 256];
  }
  __syncthreads();
  {
    const int jm = t & 63, gg = t >> 6;
    float acc[8];
#pragma unroll
    for (int u = 0; u < 8; ++u) acc[u] = b1[jm];
    for (int kk = 0; kk < 32; ++kk) {
      const float w = w1s[kk][jm];
#pragma unroll
      for (int u = 0; u < 8; ++u) acc[u] = fmaf(hs[gg * 8 + u][kk], w, acc[u]);
    }
#pragma unroll
    for (int u = 0; u < 8; ++u) mids[gg * 8 + u][jm] = fmaxf(acc[u], 0.f);
  }
  __syncthreads();
  {
    const int j = t & 31, og = t >> 5;
    float acc[4];
#pragma unroll
    for (int u = 0; u < 4; ++u) acc[u] = b2[j];
    for (int kk = 0; kk < 64; ++kk) {
      const float w = w2s[kk][j];
#pragma unroll
      for (int u = 0; u < 4; ++u) acc[u] = fmaf(mids[og * 4 + u][kk], w, acc[u]);
    }
#pragma unroll
    for (int u = 0; u < 4; ++u) {
      const int r = og * 4 + u;
      ys[r][j] = hs[r][j] + acc[u];
    }
  }
  __syncthreads();
  if (t < 32) {
    float mu = 0.f;
#pragma unroll
    for (int c = 0; c < 32; ++c) mu += ys[t][c];
    mu *= (1.f / 32.f);
    float var = 0.f;
#pragma unroll
    for (int c = 0; c < 32; ++c) {
      const float dd = ys[t][c] - mu;
      var = fmaf(dd, dd, var);
    }
    var *= (1.f / 32.f);
    const float rs = rsqrtf(var + 1e-5f);
#pragma unroll
    for (int c = 0; c < 32; ++c)
      h[(size_t)(r0 + t) * 32 + c] = (ys[t][c] - mu) * rs * g[c] + bb[c];
  }
}

// ---------------- head ----------------
__global__ __launch_bounds__(256) void headp_kernel(const float* __restrict__ h,
                                                    float* __restrict__ partial) {
  __shared__ float red[8][32];
  const int t = threadIdx.x;
  const int c = t & 31, rg = t >> 5;
  const int r0 = blockIdx.x * 64;
  float s = 0.f;
#pragma unroll
  for (int u = 0; u < 8; ++u) s += h[(size_t)(r0 + rg * 8 + u) * 32 + c];
  red[rg][c] = s;
  __syncthreads();
  if (t < 32) {
    float ss = 0.f;
#pragma unroll
    for (int u = 0; u < 8; ++u) ss += red[u][t];
    partial[blockIdx.x * 32 + t] = ss;
  }
}

__global__ __launch_bounds__(64) void headf_kernel(const float* __restrict__ partial,
                                                   const float* __restrict__ w1,
                                                   const float* __restrict__ b1,
                                                   const float* __restrict__ w2,
                                                   const float* __restrict__ b2,
                                                   float* __restrict__ out) {
  __shared__ float mls[32];
  __shared__ float tls[16];
  const int t = threadIdx.x;
  if (t < 32) {
    float s = 0.f;
    for (int bb = 0; bb < 64; ++bb) s += partial[bb * 32 + t];
    mls[t] = s * (1.f / 4096.f);
  }
  __syncthreads();
  if (t < 16) {
    float a = b1[t];
#pragma unroll
    for (int c = 0; c < 32; ++c) a = fmaf(mls[c], w1[c * 16 + t], a);
    tls[t] = tanhf(a);
  }
  __syncthreads();
  if (t == 0) {
    float o = b2[0];
#pragma unroll
    for (int jj = 0; jj < 16; ++jj) o = fmaf(tls[jj], w2[jj], o);
    out[0] = o;
  }
}

extern "C" void kernel_launch(void* const* d_in, const int* in_sizes, int n_in,
                              void* d_out, int out_size, void* d_ws, size_t ws_size,
                              hipStream_t stream) {
  const float* x      = (const float*)d_in[0];
  const float* enc_w1 = (const float*)d_in[1];
  const float* enc_b1 = (const float*)d_in[2];
  const float* enc_w2 = (const float*)d_in[3];
  const float* enc_b2 = (const float*)d_in[4];
  const float* enc_w3 = (const float*)d_in[5];
  const float* enc_b3 = (const float*)d_in[6];
  const float* wq     = (const float*)d_in[7];
  const float* bq     = (const float*)d_in[8];
  const float* wk     = (const float*)d_in[9];
  const float* bk     = (const float*)d_in[10];
  const float* wv     = (const float*)d_in[11];
  const float* bv     = (const float*)d_in[12];
  const float* wo     = (const float*)d_in[13];
  const float* bo     = (const float*)d_in[14];
  const float* ln1_g  = (const float*)d_in[15];
  const float* ln1_b  = (const float*)d_in[16];
  const float* ffn_w1 = (const float*)d_in[17];
  const float* ffn_b1 = (const float*)d_in[18];
  const float* ffn_w2 = (const float*)d_in[19];
  const float* ffn_b2 = (const float*)d_in[20];
  const float* ln2_g  = (const float*)d_in[21];
  const float* ln2_b  = (const float*)d_in[22];
  const float* head_w1 = (const float*)d_in[23];
  const float* head_b1 = (const float*)d_in[24];
  const float* head_w2 = (const float*)d_in[25];
  const float* head_b2 = (const float*)d_in[26];

  float* ws      = (float*)d_ws;
  float* latent  = ws;                    // 131072
  float* normed  = ws + 131072;           // 131072
  float* h       = ws + 262144;           // 131072
  float* q       = ws + 393216;           // 131072
  float* k       = ws + 524288;           // 131072
  float* v       = ws + 655360;           // 131072
  float* attno   = ws + 786432;           // 131072
  float* shreg   = ws + 917504;           // shared region: pool partials, then attn partials
  float* p_acc   = shreg;                 // pool: 8*131072
  float* p_deg   = shreg + 1048576;       // pool: 8*4096
  float* a_acc   = shreg;                 // attn: 8*131072
  float* a_l     = shreg + 1048576;       // attn: 8*16384
  int*   kmax2i  = (int*)(ws + 2097152);  // 8 ints (4 per transformer block)
  float* partial = ws + 2097216;          // 2048

  hipMemsetAsync(kmax2i, 0, 8 * sizeof(int), stream);

  enc_kernel<<<512, 256, 0, stream>>>(x, enc_w1, enc_b1, enc_w2, enc_b2, enc_w3, enc_b3,
                                      latent, normed);
  pool_kernel<<<dim3(64, JC), 256, 0, stream>>>(normed, latent, p_acc, p_deg);
  pool_combine<<<512, 256, 0, stream>>>(latent, p_acc, p_deg, h);

  for (int blk = 0; blk < 2; ++blk) {
    qkv_kernel<<<128, 256, 0, stream>>>(h, wq + blk * 1024, bq + blk * 32,
                                        wk + blk * 1024, bk + blk * 32,
                                        wv + blk * 1024, bv + blk * 32, q, k, v,
                                        kmax2i + blk * 4);
    attn_kernel<<<dim3(64, JC), 256, 0, stream>>>(q, k, v, kmax2i + blk * 4, a_acc, a_l);
    acombine<<<512, 256, 0, stream>>>(a_acc, a_l, attno);
    oln1_kernel<<<128, 256, 0, stream>>>(attno, wo + blk * 1024, bo + blk * 32,
                                         ln1_g + blk * 32, ln1_b + blk * 32, h);
    ffn_kernel<<<128, 256, 0, stream>>>(h, ffn_w1 + blk * 2048, ffn_b1 + blk * 64,
                                        ffn_w2 + blk * 2048, ffn_b2 + blk * 32,
                                        ln2_g + blk * 32, ln2_b + blk * 32, h);
  }

  headp_kernel<<<64, 256, 0, stream>>>(h, partial);
  headf_kernel<<<1, 64, 0, stream>>>(partial, head_w1, head_b1, head_w2, head_b2, (float*)d_out);
}

// Round 6
// 180.647 us; speedup vs baseline: 2.1544x; 1.1065x over previous
//
#include <hip/hip_runtime.h>
#include <math.h>

#define N 4096
#define DIN 512
#define D 32
#define JC 8

// ---------------- encoder: x[4096,512] -> latent[4096,32] + normed rows, fused ----------------
// R6: k-split layer 1. R5 had each of the 4 waves reading the ENTIRE 256 KB w1 (4x dup ->
// 512 MB L2) over 256 serial load-groups -> latency-bound at VALUBusy 18%. Now wave kq
// owns k-range [kq*128, kq*128+128) for ALL 8 rows (w1 read once per block, 4x fewer
// loads per wave, ring-prefetched 16 ahead); partials reduced via LDS h1p with bias+relu
// in the reduce. x reads are LDS broadcasts. FP reassociation: 4 k-chunks summed after.
__global__ __launch_bounds__(256) void enc_kernel(
    const float* __restrict__ x,
    const float* __restrict__ w1, const float* __restrict__ b1,
    const float* __restrict__ w2, const float* __restrict__ b2,
    const float* __restrict__ w3, const float* __restrict__ b3,
    float* __restrict__ latent, float* __restrict__ normed) {
  __shared__ float xs[8][512];       // 16 KB
  __shared__ float h1p[4][8][128];   // 16 KB layer-1 partials (per k-quarter)
  __shared__ float h1s[8][128];      // 4 KB
  __shared__ float h2s[8][64];       // 2 KB
  __shared__ float w2s[128][64];     // 32 KB
  __shared__ float w3s[64][32];      // 8 KB   -> total 78 KB = 2 blocks/CU
  const int t = threadIdx.x;
  const int r0 = blockIdx.x * 8;

  // stage x rows + w2 + w3 into LDS (one barrier covers all)
  const float4* xg = (const float4*)(x + (size_t)r0 * DIN);
  float4* xl = (float4*)&xs[0][0];
#pragma unroll
  for (int i = 0; i < 4; ++i) xl[t + i * 256] = xg[t + i * 256];
  float4* w2l = (float4*)&w2s[0][0];
  const float4* w2g = (const float4*)w2;
#pragma unroll
  for (int i = 0; i < 8; ++i) w2l[t + i * 256] = w2g[t + i * 256];
  float4* w3l = (float4*)&w3s[0][0];
  const float4* w3g = (const float4*)w3;
#pragma unroll
  for (int i = 0; i < 2; ++i) w3l[t + i * 256] = w3g[t + i * 256];
  __syncthreads();

  // layer 1: 512 -> 128. wave kq handles its k-quarter for all 8 rows x 2 cols.
  {
    const int jc2 = (t & 63) * 2;
    const int kq = t >> 6;
    const int kb = kq * 128;
    float a0[8], a1[8];
#pragma unroll
    for (int r = 0; r < 8; ++r) { a0[r] = 0.f; a1[r] = 0.f; }
    const float* wp = w1 + (size_t)kb * 128 + jc2;

#define ENC_LD4(P0, P1, P2, P3, KK)                          \
    P0 = *(const float2*)&wp[(size_t)(KK) * 128];            \
    P1 = *(const float2*)&wp[(size_t)((KK) + 1) * 128];      \
    P2 = *(const float2*)&wp[(size_t)((KK) + 2) * 128];      \
    P3 = *(const float2*)&wp[(size_t)((KK) + 3) * 128];

#define ENC_STEP(W0, WA, WB, WC, KK)                                   \
    {                                                                  \
      _Pragma("unroll")                                                \
      for (int r = 0; r < 8; ++r) {                                    \
        const float4 xv = *(const float4*)&xs[r][kb + (KK)];           \
        a0[r] = fmaf(xv.x, W0.x, a0[r]); a1[r] = fmaf(xv.x, W0.y, a1[r]); \
        a0[r] = fmaf(xv.y, WA.x, a0[r]); a1[r] = fmaf(xv.y, WA.y, a1[r]); \
        a0[r] = fmaf(xv.z, WB.x, a0[r]); a1[r] = fmaf(xv.z, WB.y, a1[r]); \
        a0[r] = fmaf(xv.w, WC.x, a0[r]); a1[r] = fmaf(xv.w, WC.y, a1[r]); \
      }                                                                \
    }

    float2 A0, A1, A2, A3, B0, B1, B2, B3, C0, C1, C2, C3, D0, D1, D2, D3;
    ENC_LD4(A0, A1, A2, A3, 0)
    ENC_LD4(B0, B1, B2, B3, 4)
    ENC_LD4(C0, C1, C2, C3, 8)
    ENC_LD4(D0, D1, D2, D3, 12)
    for (int kk = 0; kk < 128; kk += 16) {
      ENC_STEP(A0, A1, A2, A3, kk + 0);
      if (kk + 16 < 128) { ENC_LD4(A0, A1, A2, A3, kk + 16) }
      ENC_STEP(B0, B1, B2, B3, kk + 4);
      if (kk + 20 < 128) { ENC_LD4(B0, B1, B2, B3, kk + 20) }
      ENC_STEP(C0, C1, C2, C3, kk + 8);
      if (kk + 24 < 128) { ENC_LD4(C0, C1, C2, C3, kk + 24) }
      ENC_STEP(D0, D1, D2, D3, kk + 12);
      if (kk + 28 < 128) { ENC_LD4(D0, D1, D2, D3, kk + 28) }
    }
#undef ENC_STEP
#undef ENC_LD4
#pragma unroll
    for (int r = 0; r < 8; ++r) {
      h1p[kq][r][jc2] = a0[r];
      h1p[kq][r][jc2 + 1] = a1[r];
    }
  }
  __syncthreads();

  // reduce the 4 k-quarter partials + bias + relu (1024 outputs)
#pragma unroll
  for (int e0 = 0; e0 < 1024; e0 += 256) {
    const int e = e0 + t;
    const int r = e >> 7, c = e & 127;
    const float s = b1[c] + ((h1p[0][r][c] + h1p[1][r][c]) + (h1p[2][r][c] + h1p[3][r][c]));
    h1s[r][c] = fmaxf(s, 0.f);
  }
  __syncthreads();

  // layer 2: 128 -> 64, relu. weights from LDS (w2s), h1 broadcast reads
  {
    const int j = t & 63, rg = t >> 6;
    const int ra = rg * 2, rb = ra + 1;
    float a0 = b2[j], a1 = b2[j];
#pragma unroll 8
    for (int kk = 0; kk < 128; ++kk) {
      const float w = w2s[kk][j];
      a0 = fmaf(h1s[ra][kk], w, a0);
      a1 = fmaf(h1s[rb][kk], w, a1);
    }
    h2s[ra][j] = fmaxf(a0, 0.f);
    h2s[rb][j] = fmaxf(a1, 0.f);
  }
  __syncthreads();

  // layer 3: 64 -> 32 + fused row-normalize (shfl reduce over the 32 j-lanes)
  {
    const int j = t & 31, og = t >> 5;  // 8 rows, 1 per group
    float acc = b3[j];
#pragma unroll 8
    for (int kk = 0; kk < 64; ++kk) acc = fmaf(h2s[og][kk], w3s[kk][j], acc);
    float s2 = acc * acc;
    s2 += __shfl_xor(s2, 1);
    s2 += __shfl_xor(s2, 2);
    s2 += __shfl_xor(s2, 4);
    s2 += __shfl_xor(s2, 8);
    s2 += __shfl_xor(s2, 16);
    const float inv = 1.0f / (sqrtf(s2) + 1e-12f);
    const size_t off = (size_t)(r0 + og) * D + j;
    latent[off] = acc;
    normed[off] = acc * inv;
  }
}

// ---------------- graph pool partials: block (bi, bj) covers 64 i-rows x 512 j ----------------
__global__ __launch_bounds__(256) void pool_kernel(const float* __restrict__ normed,
                                                   const float* __restrict__ latent,
                                                   float* __restrict__ pacc,
                                                   float* __restrict__ pdeg) {
  __shared__ float smem[8192 + 256];
  float* nt = smem;
  float* lt = smem + 4096;
  float* degr = smem + 8192;
  const int t = threadIdx.x;
  const int il = t & 63, g = t >> 6;
  const int i0 = blockIdx.x * 64;
  const int j0 = blockIdx.y * 512;

  float ni[32];
  const float* nrow = normed + (size_t)(i0 + il) * D;
#pragma unroll
  for (int c = 0; c < 32; ++c) ni[c] = nrow[c];

  float acc[32];
#pragma unroll
  for (int c = 0; c < 32; ++c) acc[c] = 0.f;
  float deg = 0.f;

  for (int jt = j0; jt < j0 + 512; jt += 128) {
    __syncthreads();
    const float4* ng = (const float4*)(normed + (size_t)jt * D);
    const float4* lg = (const float4*)(latent + (size_t)jt * D);
    float4* ntl = (float4*)nt;
    float4* ltl = (float4*)lt;
#pragma unroll
    for (int i = 0; i < 4; ++i) {
      ntl[t + i * 256] = ng[t + i * 256];
      ltl[t + i * 256] = lg[t + i * 256];
    }
    __syncthreads();
    for (int jj = g; jj < 128; jj += 4) {
      const float* nr = nt + jj * 32;
      float s = 0.f;
#pragma unroll
      for (int c = 0; c < 32; ++c) s = fmaf(ni[c], nr[c], s);
      if (s >= 0.9f) {
        deg += 1.f;
        const float* lrow = lt + jj * 32;
#pragma unroll
        for (int c = 0; c < 32; ++c) acc[c] += lrow[c];
      }
    }
  }
  __syncthreads();
  float* accr = smem;
#pragma unroll
  for (int c = 0; c < 32; ++c) accr[(g * 64 + il) * 32 + c] = acc[c];
  degr[t] = deg;
  __syncthreads();
  for (int e = t; e < 64 * 32; e += 256) {
    const float s = accr[e] + accr[2048 + e] + accr[4096 + e] + accr[6144 + e];
    pacc[((size_t)blockIdx.y * N + i0 + (e >> 5)) * 32 + (e & 31)] = s;
  }
  if (t < 64) {
    pdeg[(size_t)blockIdx.y * N + i0 + t] = degr[t] + degr[64 + t] + degr[128 + t] + degr[192 + t];
  }
}

// ---------------- combine pool partials -> h = latent + (mask@latent)/deg ----------------
__global__ __launch_bounds__(256) void pool_combine(const float* __restrict__ latent,
                                                    const float* __restrict__ pacc,
                                                    const float* __restrict__ pdeg,
                                                    float* __restrict__ h) {
  const int e = blockIdx.x * 256 + threadIdx.x;
  const int i = e >> 5;
  float s = 0.f, dg = 0.f;
#pragma unroll
  for (int gch = 0; gch < JC; ++gch) {
    s += pacc[(size_t)gch * N * 32 + e];
    dg += pdeg[(size_t)gch * N + i];
  }
  h[e] = latent[e] + s / dg;
}

// ---------------- fused QKV projection (q pre-scaled by log2e/sqrt(8)) + k-norm max ----------------
__global__ __launch_bounds__(256) void qkv_kernel(
    const float* __restrict__ h,
    const float* __restrict__ wq, const float* __restrict__ bq,
    const float* __restrict__ wk, const float* __restrict__ bk,
    const float* __restrict__ wv, const float* __restrict__ bv,
    float* __restrict__ q, float* __restrict__ k, float* __restrict__ v,
    int* __restrict__ kmax2i) {
  __shared__ float hs[32][32];
  __shared__ float wsm[3][32][32];
  __shared__ int kred[4];
  const int t = threadIdx.x;
  const int r0 = blockIdx.x * 32;
  if (t < 4) kred[t] = 0;
  ((float4*)&hs[0][0])[t] = ((const float4*)(h + (size_t)r0 * 32))[t];
  ((float4*)&wsm[0][0][0])[t] = ((const float4*)wq)[t];
  ((float4*)&wsm[1][0][0])[t] = ((const float4*)wk)[t];
  ((float4*)&wsm[2][0][0])[t] = ((const float4*)wv)[t];
  __syncthreads();
  const int j = t & 31, og = t >> 5;
  const int head = j >> 3;
  float aq[4], ak[4], av[4];
#pragma unroll
  for (int u = 0; u < 4; ++u) { aq[u] = bq[j]; ak[u] = bk[j]; av[u] = bv[j]; }
  for (int kk = 0; kk < 32; ++kk) {
    const float wqv = wsm[0][kk][j], wkv = wsm[1][kk][j], wvv = wsm[2][kk][j];
#pragma unroll
    for (int u = 0; u < 4; ++u) {
      const float hh = hs[og * 4 + u][kk];
      aq[u] = fmaf(hh, wqv, aq[u]);
      ak[u] = fmaf(hh, wkv, ak[u]);
      av[u] = fmaf(hh, wvv, av[u]);
    }
  }
  const float scale = 1.4426950408889634f * 0.35355339059327373f;  // log2(e)/sqrt(8)
#pragma unroll
  for (int u = 0; u < 4; ++u) {
    const size_t off = (size_t)(r0 + og * 4 + u) * 32 + j;
    q[off] = aq[u] * scale;
    k[off] = ak[u];
    v[off] = av[u];
  }
  // per-(row,head) ||k8||^2 via shfl over the 8 lanes of this head; block-max; global atomicMax
#pragma unroll
  for (int u = 0; u < 4; ++u) {
    float s2 = ak[u] * ak[u];
    s2 += __shfl_xor(s2, 1);
    s2 += __shfl_xor(s2, 2);
    s2 += __shfl_xor(s2, 4);
    if ((j & 7) == 0) atomicMax(&kred[head], __float_as_int(s2));
  }
  __syncthreads();
  if (t < 4) atomicMax(&kmax2i[t], kred[t]);
}

// ---------------- attention partials: block (rowBlk, jChunk); 64 rows x 512 j ----------------
// R6: + T14 reg-staged prefetch. R5's per-tile global->LDS load sat serially between the
// two barriers (~300-600 cyc exposed x 8 tiles at 2 waves/SIMD). Now the next tile's 4
// float4 loads are issued right after the post-write barrier and consumed by ds_write one
// iteration later -- latency hides under the 3.3K-cyc compute phase. +16 VGPR (~136,
// within the (2,2) 256-reg budget). Math/order unchanged.
__global__ __launch_bounds__(256) __attribute__((amdgpu_waves_per_eu(2, 2)))
void attn_kernel(const float* __restrict__ q,
                 const float* __restrict__ k,
                 const float* __restrict__ v,
                 const int* __restrict__ kmax2i,
                 float* __restrict__ apacc,
                 float* __restrict__ apl) {
  __shared__ float4 tiles[1024];  // kls[64*8] | vls[64*8], chunk-XOR swizzled
  float4* kls = tiles;
  float4* vls = tiles + 512;
  const int t = threadIdx.x;
  const int jg = t & 7, head = (t >> 3) & 3, rg = t >> 5;
  const int r0 = blockIdx.x * 64;
  const int j0 = blockIdx.y * (N / JC);

  const float km2 = __int_as_float(kmax2i[head]);

  float4 qa[8], qb[8], accA[8], accB[8];
  float mneg[8], l[8];
#pragma unroll
  for (int u = 0; u < 8; ++u) {
    const float* qr = q + (size_t)(r0 + rg * 8 + u) * 32 + head * 8;
    qa[u] = ((const float4*)qr)[0];
    qb[u] = ((const float4*)qr)[1];
    const float qn2 = qa[u].x * qa[u].x + qa[u].y * qa[u].y + qa[u].z * qa[u].z + qa[u].w * qa[u].w +
                      qb[u].x * qb[u].x + qb[u].y * qb[u].y + qb[u].z * qb[u].z + qb[u].w * qb[u].w;
    mneg[u] = -sqrtf(qn2 * km2);
    l[u] = 0.f;
    accA[u] = make_float4(0.f, 0.f, 0.f, 0.f);
    accB[u] = make_float4(0.f, 0.f, 0.f, 0.f);
  }

  // prologue: load tile 0 into registers
  float4 kr0, kr1, vr0, vr1;
  {
    const float4* kg = (const float4*)(k + (size_t)j0 * 32);
    const float4* vg = (const float4*)(v + (size_t)j0 * 32);
    kr0 = kg[t]; kr1 = kg[t + 256];
    vr0 = vg[t]; vr1 = vg[t + 256];
  }

  // precomputed swizzle slots for the two staged quarters
  const int rA = t >> 3, slotA = (t & 7) ^ (rA & 7);
  const int g1 = t + 256;
  const int rB = g1 >> 3, slotB = (g1 & 7) ^ (rB & 7);

  const int h2 = head * 2;
  const int s0 = h2 ^ jg, s1 = (h2 + 1) ^ jg;
  for (int jt = j0; jt < j0 + (N / JC); jt += 64) {
    __syncthreads();
    kls[rA * 8 + slotA] = kr0;
    kls[rB * 8 + slotB] = kr1;
    vls[rA * 8 + slotA] = vr0;
    vls[rB * 8 + slotB] = vr1;
    __syncthreads();
    if (jt + 64 < j0 + (N / JC)) {
      const float4* kg = (const float4*)(k + (size_t)(jt + 64) * 32);
      const float4* vg = (const float4*)(v + (size_t)(jt + 64) * 32);
      kr0 = kg[t]; kr1 = kg[t + 256];
      vr0 = vg[t]; vr1 = vg[t + 256];
    }
#pragma unroll 2
    for (int it = 0; it < 8; ++it) {
      const int jj = it * 8 + jg;
      const float4 ka = kls[jj * 8 + s0];
      const float4 kb = kls[jj * 8 + s1];
      const float4 va = vls[jj * 8 + s0];
      const float4 vb = vls[jj * 8 + s1];
#pragma unroll
      for (int u = 0; u < 8; ++u) {
        float s = fmaf(qa[u].x, ka.x, mneg[u]);
        s = fmaf(qa[u].y, ka.y, s);
        s = fmaf(qa[u].z, ka.z, s);
        s = fmaf(qa[u].w, ka.w, s);
        s = fmaf(qb[u].x, kb.x, s);
        s = fmaf(qb[u].y, kb.y, s);
        s = fmaf(qb[u].z, kb.z, s);
        s = fmaf(qb[u].w, kb.w, s);
        const float p = __builtin_amdgcn_exp2f(s);
        l[u] += p;
        accA[u].x = fmaf(p, va.x, accA[u].x);
        accA[u].y = fmaf(p, va.y, accA[u].y);
        accA[u].z = fmaf(p, va.z, accA[u].z);
        accA[u].w = fmaf(p, va.w, accA[u].w);
        accB[u].x = fmaf(p, vb.x, accB[u].x);
        accB[u].y = fmaf(p, vb.y, accB[u].y);
        accB[u].z = fmaf(p, vb.z, accB[u].z);
        accB[u].w = fmaf(p, vb.w, accB[u].w);
      }
    }
  }
  // butterfly-reduce the 8 jg partials (jg = lane bits 0..2); all lanes end with the sum
#pragma unroll
  for (int u = 0; u < 8; ++u) {
#pragma unroll
    for (int m = 1; m <= 4; m <<= 1) {
      accA[u].x += __shfl_xor(accA[u].x, m);
      accA[u].y += __shfl_xor(accA[u].y, m);
      accA[u].z += __shfl_xor(accA[u].z, m);
      accA[u].w += __shfl_xor(accA[u].w, m);
      accB[u].x += __shfl_xor(accB[u].x, m);
      accB[u].y += __shfl_xor(accB[u].y, m);
      accB[u].z += __shfl_xor(accB[u].z, m);
      accB[u].w += __shfl_xor(accB[u].w, m);
      l[u] += __shfl_xor(l[u], m);
    }
  }
  if (jg == 0) {
#pragma unroll
    for (int u = 0; u < 8; ++u) {
      const int row = r0 + rg * 8 + u;
      float* ap = apacc + (size_t)blockIdx.y * N * 32 + (size_t)row * 32 + head * 8;
      ((float4*)ap)[0] = accA[u];
      ((float4*)ap)[1] = accB[u];
      apl[(size_t)blockIdx.y * N * 4 + (size_t)row * 4 + head] = l[u];
    }
  }
}

// ---------------- combine attention partials ----------------
__global__ __launch_bounds__(256) void acombine(const float* __restrict__ apacc,
                                                const float* __restrict__ apl,
                                                float* __restrict__ attno) {
  const int e = blockIdx.x * 256 + threadIdx.x;  // < N*32
  const int row = e >> 5;
  const int hh = (e >> 3) & 3;
  float L = 0.f, S = 0.f;
#pragma unroll
  for (int jc = 0; jc < JC; ++jc) {
    L += apl[(size_t)jc * N * 4 + row * 4 + hh];
    S += apacc[(size_t)jc * N * 32 + e];
  }
  attno[e] = S / L;
}

// ---------------- O-projection + residual + LayerNorm1 ----------------
__global__ __launch_bounds__(256) void oln1_kernel(const float* __restrict__ attno,
                                                   const float* __restrict__ wo,
                                                   const float* __restrict__ bo,
                                                   const float* __restrict__ g,
                                                   const float* __restrict__ b,
                                                   float* __restrict__ h) {
  __shared__ float als[32][32];
  __shared__ float wols[32][32];
  __shared__ float ys[32][33];
  const int t = threadIdx.x;
  const int r0 = blockIdx.x * 32;
  ((float4*)&als[0][0])[t] = ((const float4*)(attno + (size_t)r0 * 32))[t];
  ((float4*)&wols[0][0])[t] = ((const float4*)wo)[t];
  __syncthreads();
  const int j = t & 31, og = t >> 5;
  float acc[4];
#pragma unroll
  for (int u = 0; u < 4; ++u) acc[u] = bo[j];
  for (int kk = 0; kk < 32; ++kk) {
    const float w = wols[kk][j];
#pragma unroll
    for (int u = 0; u < 4; ++u) acc[u] = fmaf(als[og * 4 + u][kk], w, acc[u]);
  }
#pragma unroll
  for (int u = 0; u < 4; ++u) {
    const int r = og * 4 + u;
    ys[r][j] = h[(size_t)(r0 + r) * 32 + j] + acc[u];
  }
  __syncthreads();
  if (t < 32) {
    float mu = 0.f;
#pragma unroll
    for (int c = 0; c < 32; ++c) mu += ys[t][c];
    mu *= (1.f / 32.f);
    float var = 0.f;
#pragma unroll
    for (int c = 0; c < 32; ++c) {
      const float dd = ys[t][c] - mu;
      var = fmaf(dd, dd, var);
    }
    var *= (1.f / 32.f);
    const float rs = rsqrtf(var + 1e-5f);
#pragma unroll
    for (int c = 0; c < 32; ++c)
      h[(size_t)(r0 + t) * 32 + c] = (ys[t][c] - mu) * rs * g[c] + b[c];
  }
}

// ---------------- FFN + residual + LayerNorm2 ----------------
__global__ __launch_bounds__(256) void ffn_kernel(const float* __restrict__ hin,
                                                  const float* __restrict__ w1,
                                                  const float* __restrict__ b1,
                                                  const float* __restrict__ w2,
                                                  const float* __restrict__ b2,
                                                  const float* __restrict__ g,
                                                  const float* __restrict__ bb,
                                                  float* __restrict__ h) {
  __shared__ float hs[32][32];
  __shared__ float w1s[32][64];
  __shared__ float w2s[64][32];
  __shared__ float mids[32][64];
  __shared__ float ys[32][33];
  const int t = threadIdx.x;
  const int r0 = blockIdx.x * 32;
  ((float4*)&hs[0][0])[t] = ((const float4*)(hin + (size_t)r0 * 32))[t];
#pragma unroll
  for (int i = 0; i < 2; ++i) {
    ((float4*)&w1s[0][0])[t + i * 256] = ((const float4*)w1)[t + i * 256];
    ((float4*)&w2s[0][0])[t + i * 256] = ((const float4*)w2)[t + i * 256];
  }
  __syncthreads();
  {
    const int jm = t & 63, gg = t >> 6;
    float acc[8];
#pragma unroll
    for (int u = 0; u < 8; ++u) acc[u] = b1[jm];
    for (int kk = 0; kk < 32; ++kk) {
      const float w = w1s[kk][jm];
#pragma unroll
      for (int u = 0; u < 8; ++u) acc[u] = fmaf(hs[gg * 8 + u][kk], w, acc[u]);
    }
#pragma unroll
    for (int u = 0; u < 8; ++u) mids[gg * 8 + u][jm] = fmaxf(acc[u], 0.f);
  }
  __syncthreads();
  {
    const int j = t & 31, og = t >> 5;
    float acc[4];
#pragma unroll
    for (int u = 0; u < 4; ++u) acc[u] = b2[j];
    for (int kk = 0; kk < 64; ++kk) {
      const float w = w2s[kk][j];
#pragma unroll
      for (int u = 0; u < 4; ++u) acc[u] = fmaf(mids[og * 4 + u][kk], w, acc[u]);
    }
#pragma unroll
    for (int u = 0; u < 4; ++u) {
      const int r = og * 4 + u;
      ys[r][j] = hs[r][j] + acc[u];
    }
  }
  __syncthreads();
  if (t < 32) {
    float mu = 0.f;
#pragma unroll
    for (int c = 0; c < 32; ++c) mu += ys[t][c];
    mu *= (1.f / 32.f);
    float var = 0.f;
#pragma unroll
    for (int c = 0; c < 32; ++c) {
      const float dd = ys[t][c] - mu;
      var = fmaf(dd, dd, var);
    }
    var *= (1.f / 32.f);
    const float rs = rsqrtf(var + 1e-5f);
#pragma unroll
    for (int c = 0; c < 32; ++c)
      h[(size_t)(r0 + t) * 32 + c] = (ys[t][c] - mu) * rs * g[c] + bb[c];
  }
}

// ---------------- head ----------------
__global__ __launch_bounds__(256) void headp_kernel(const float* __restrict__ h,
                                                    float* __restrict__ partial) {
  __shared__ float red[8][32];
  const int t = threadIdx.x;
  const int c = t & 31, rg = t >> 5;
  const int r0 = blockIdx.x * 64;
  float s = 0.f;
#pragma unroll
  for (int u = 0; u < 8; ++u) s += h[(size_t)(r0 + rg * 8 + u) * 32 + c];
  red[rg][c] = s;
  __syncthreads();
  if (t < 32) {
    float ss = 0.f;
#pragma unroll
    for (int u = 0; u < 8; ++u) ss += red[u][t];
    partial[blockIdx.x * 32 + t] = ss;
  }
}

__global__ __launch_bounds__(64) void headf_kernel(const float* __restrict__ partial,
                                                   const float* __restrict__ w1,
                                                   const float* __restrict__ b1,
                                                   const float* __restrict__ w2,
                                                   const float* __restrict__ b2,
                                                   float* __restrict__ out) {
  __shared__ float mls[32];
  __shared__ float tls[16];
  const int t = threadIdx.x;
  if (t < 32) {
    float s = 0.f;
    for (int bb = 0; bb < 64; ++bb) s += partial[bb * 32 + t];
    mls[t] = s * (1.f / 4096.f);
  }
  __syncthreads();
  if (t < 16) {
    float a = b1[t];
#pragma unroll
    for (int c = 0; c < 32; ++c) a = fmaf(mls[c], w1[c * 16 + t], a);
    tls[t] = tanhf(a);
  }
  __syncthreads();
  if (t == 0) {
    float o = b2[0];
#pragma unroll
    for (int jj = 0; jj < 16; ++jj) o = fmaf(tls[jj], w2[jj], o);
    out[0] = o;
  }
}

extern "C" void kernel_launch(void* const* d_in, const int* in_sizes, int n_in,
                              void* d_out, int out_size, void* d_ws, size_t ws_size,
                              hipStream_t stream) {
  const float* x      = (const float*)d_in[0];
  const float* enc_w1 = (const float*)d_in[1];
  const float* enc_b1 = (const float*)d_in[2];
  const float* enc_w2 = (const float*)d_in[3];
  const float* enc_b2 = (const float*)d_in[4];
  const float* enc_w3 = (const float*)d_in[5];
  const float* enc_b3 = (const float*)d_in[6];
  const float* wq     = (const float*)d_in[7];
  const float* bq     = (const float*)d_in[8];
  const float* wk     = (const float*)d_in[9];
  const float* bk     = (const float*)d_in[10];
  const float* wv     = (const float*)d_in[11];
  const float* bv     = (const float*)d_in[12];
  const float* wo     = (const float*)d_in[13];
  const float* bo     = (const float*)d_in[14];
  const float* ln1_g  = (const float*)d_in[15];
  const float* ln1_b  = (const float*)d_in[16];
  const float* ffn_w1 = (const float*)d_in[17];
  const float* ffn_b1 = (const float*)d_in[18];
  const float* ffn_w2 = (const float*)d_in[19];
  const float* ffn_b2 = (const float*)d_in[20];
  const float* ln2_g  = (const float*)d_in[21];
  const float* ln2_b  = (const float*)d_in[22];
  const float* head_w1 = (const float*)d_in[23];
  const float* head_b1 = (const float*)d_in[24];
  const float* head_w2 = (const float*)d_in[25];
  const float* head_b2 = (const float*)d_in[26];

  float* ws      = (float*)d_ws;
  float* latent  = ws;                    // 131072
  float* normed  = ws + 131072;           // 131072
  float* h       = ws + 262144;           // 131072
  float* q       = ws + 393216;           // 131072
  float* k       = ws + 524288;           // 131072
  float* v       = ws + 655360;           // 131072
  float* attno   = ws + 786432;           // 131072
  float* shreg   = ws + 917504;           // shared region: pool partials, then attn partials
  float* p_acc   = shreg;                 // pool: 8*131072
  float* p_deg   = shreg + 1048576;       // pool: 8*4096
  float* a_acc   = shreg;                 // attn: 8*131072
  float* a_l     = shreg + 1048576;       // attn: 8*16384
  int*   kmax2i  = (int*)(ws + 2097152);  // 8 ints (4 per transformer block)
  float* partial = ws + 2097216;          // 2048

  hipMemsetAsync(kmax2i, 0, 8 * sizeof(int), stream);

  enc_kernel<<<512, 256, 0, stream>>>(x, enc_w1, enc_b1, enc_w2, enc_b2, enc_w3, enc_b3,
                                      latent, normed);
  pool_kernel<<<dim3(64, JC), 256, 0, stream>>>(normed, latent, p_acc, p_deg);
  pool_combine<<<512, 256, 0, stream>>>(latent, p_acc, p_deg, h);

  for (int blk = 0; blk < 2; ++blk) {
    qkv_kernel<<<128, 256, 0, stream>>>(h, wq + blk * 1024, bq + blk * 32,
                                        wk + blk * 1024, bk + blk * 32,
                                        wv + blk * 1024, bv + blk * 32, q, k, v,
                                        kmax2i + blk * 4);
    attn_kernel<<<dim3(64, JC), 256, 0, stream>>>(q, k, v, kmax2i + blk * 4, a_acc, a_l);
    acombine<<<512, 256, 0, stream>>>(a_acc, a_l, attno);
    oln1_kernel<<<128, 256, 0, stream>>>(attno, wo + blk * 1024, bo + blk * 32,
                                         ln1_g + blk * 32, ln1_b + blk * 32, h);
    ffn_kernel<<<128, 256, 0, stream>>>(h, ffn_w1 + blk * 2048, ffn_b1 + blk * 64,
                                        ffn_w2 + blk * 2048, ffn_b2 + blk * 32,
                                        ln2_g + blk * 32, ln2_b + blk * 32, h);
  }

  headp_kernel<<<64, 256, 0, stream>>>(h, partial);
  headf_kernel<<<1, 64, 0, stream>>>(partial, head_w1, head_b1, head_w2, head_b2, (float*)d_out);
}